// Round 4
// 4417.608 us; speedup vs baseline: 1.7929x; 1.7929x over previous
//
#include <hip/hip_runtime.h>
#include <stdint.h>

#define DEV static __device__ __forceinline__

typedef float f32x4 __attribute__((ext_vector_type(4)));
typedef float f32x2 __attribute__((ext_vector_type(2)));
typedef unsigned int u32x4 __attribute__((ext_vector_type(4)));
typedef _Float16 f16x8 __attribute__((ext_vector_type(8)));
typedef unsigned long long u64;
typedef unsigned int u32;

DEV float sigm(float x) { return __fdividef(1.0f, 1.0f + __expf(-x)); }
DEV float tanh_(float x) { return 1.0f - __fdividef(2.0f, __expf(2.0f * x) + 1.0f); }

DEV f32x4 mfma16(f16x8 a, f16x8 b, f32x4 c) {
    return __builtin_amdgcn_mfma_f32_16x16x32_f16(a, b, c, 0, 0, 0);
}

// flag ops stay __hip_atomic (R7-validated); poll loops contain no LDS ops so
// flat-op lgkmcnt aliasing cannot serialize anything there.
DEV int aload_i(const int* p) { return __hip_atomic_load(p, __ATOMIC_RELAXED, __HIP_MEMORY_SCOPE_AGENT); }
DEV void astore_i(int* p, int v) { __hip_atomic_store(p, v, __ATOMIC_RELAXED, __HIP_MEMORY_SCOPE_AGENT); }
DEV u64 aload_u64(const void* p) { return __hip_atomic_load((const u64*)p, __ATOMIC_RELAXED, __HIP_MEMORY_SCOPE_AGENT); }

// LLC-coherent (sc0 sc1) vmcnt-only data movement — pipelines, no lgkmcnt alias.
DEV f16x8 gload_h(const _Float16* p) {
    f16x8 v;
    asm volatile("global_load_dwordx4 %0, %1, off sc0 sc1" : "=v"(v) : "v"(p));
    return v;
}
DEV void gstore_u64(void* p, u64 v) {
    asm volatile("global_store_dwordx2 %0, %1, off sc0 sc1" :: "v"(p), "v"(v) : "memory");
}
DEV void vmwait8(f16x8& a0, f16x8& a1, f16x8& a2, f16x8& a3,
                 f16x8& a4, f16x8& a5, f16x8& a6, f16x8& a7) {
    asm volatile("s_waitcnt vmcnt(0)"
        : "+v"(a0), "+v"(a1), "+v"(a2), "+v"(a3), "+v"(a4), "+v"(a5), "+v"(a6), "+v"(a7)
        :: "memory");
}

// ---------------- fp8 (E4M3 OCP on gfx950) helpers ----------------
// out0 backward half stores 16*h as fp8; the 1/16 is pre-folded into the
// k>=256 columns of W_ih1 at conversion.
DEV u32 pk_fp8x4(float a, float b, float c, float d) {
    int v = __builtin_amdgcn_cvt_pk_fp8_f32(a, b, 0, false);
    v = __builtin_amdgcn_cvt_pk_fp8_f32(c, d, v, true);
    return (u32)v;
}
DEV f16x8 unpk_fp8x8(u64 w) {
    u32 w0 = (u32)w, w1 = (u32)(w >> 32);
    f32x2 p0 = __builtin_amdgcn_cvt_pk_f32_fp8((int)w0, false);
    f32x2 p1 = __builtin_amdgcn_cvt_pk_f32_fp8((int)w0, true);
    f32x2 p2 = __builtin_amdgcn_cvt_pk_f32_fp8((int)w1, false);
    f32x2 p3 = __builtin_amdgcn_cvt_pk_f32_fp8((int)w1, true);
    f16x8 r;
    r[0] = (_Float16)p0[0]; r[1] = (_Float16)p0[1];
    r[2] = (_Float16)p1[0]; r[3] = (_Float16)p1[1];
    r[4] = (_Float16)p2[0]; r[5] = (_Float16)p2[1];
    r[6] = (_Float16)p3[0]; r[7] = (_Float16)p3[1];
    return r;
}

// ---------------- packing pre-passes ----------------
__global__ __launch_bounds__(256) void cvt_f16s(const float* __restrict__ src, _Float16* __restrict__ dst, int n, float sc) {
    int o = blockIdx.x * 256 + threadIdx.x;
    if (o < n) dst[o] = (_Float16)(src[o] * sc);
}
// W_ih1: scale k>=256 columns by 1/16 only when backward half of x1 is fp8 (16x pre-scale)
__global__ __launch_bounds__(256) void cvt_wih1(const float* __restrict__ src, _Float16* __restrict__ dst, int n, int fp8half) {
    int o = blockIdx.x * 256 + threadIdx.x;
    if (o < n) {
        float sc = (fp8half && ((o & 511) >= 256)) ? 0.0625f : 1.0f;
        dst[o] = (_Float16)(src[o] * sc);
    }
}
__global__ __launch_bounds__(256) void pad_wih0_f16(const float* __restrict__ src, _Float16* __restrict__ dst) {
    int o = blockIdx.x * 256 + threadIdx.x;   // 32768
    int k = o & 31, r = o >> 5;
    dst[o] = (k < 16) ? (_Float16)src[r * 16 + k] : (_Float16)0.f;
}
__global__ __launch_bounds__(256) void pad_x_f16(const float* __restrict__ src, _Float16* __restrict__ dst) {
    int o = blockIdx.x * 256 + threadIdx.x;   // 8388608
    int k = o & 31;
    int t = (o >> 5) & 511;
    int b = o >> 14;
    dst[o] = (k < 16) ? (_Float16)src[((size_t)b * 512 + t) * 16 + k] : (_Float16)0.f;
}
__global__ __launch_bounds__(256) void transpose_fcw(const float* __restrict__ src, float* __restrict__ dst) {
    int o = blockIdx.x * 256 + threadIdx.x;   // 32768
    int j = o >> 6, l = o & 63;
    dst[o] = src[l * 512 + j];
}

// LDS W slice: 16B segment index for (jj in [0,16), gate, c5 = k0*4+q), XOR swizzle
DEV int wseg(int jj, int g, int c5) { return jj * 128 + g * 32 + (c5 ^ (jj & 7)); }

// ---------------- layer 0 persistent (dataflow-sync) ----------------
// Flags PACKED: one 64B line of 16 ints per (slot, isl) -> poll = 1 LLC line.
// out0A (dir0, f16): [t][jblk][row Bc][16] — 2KB contiguous per block-step.
// out0B (dir1): f16 same layout, or fp8 (scale 16) 1KB per block-step.
__global__ __launch_bounds__(256) void l0_persist(
    int S, int sbits, int Bc, int b0, int useFp8,
    const _Float16* __restrict__ xpad,
    const _Float16* __restrict__ WhhF, const _Float16* __restrict__ WhhB,
    const _Float16* __restrict__ WihF, const _Float16* __restrict__ WihB,
    const float* __restrict__ bF, const float* __restrict__ bB,
    _Float16* __restrict__ hring, int* __restrict__ seq,
    _Float16* __restrict__ out0A, unsigned char* __restrict__ out0B)
{
    __shared__ _Float16 recW[16384];   // 32KB
    __shared__ _Float16 hstage[1024];  // 2KB
    int tid = threadIdx.x;
    int wave = tid >> 6, lane = tid & 63, l15 = lane & 15, q = lane >> 4;
    int jblk = blockIdx.x & 15;
    int isl = blockIdx.x >> 4;
    int NI = 2 * S;
    int dir = isl >> sbits, strip = isl & (S - 1);

    const _Float16* Whh = dir ? WhhB : WhhF;
    const _Float16* Wih = dir ? WihB : WihF;
    const float* bias = dir ? bB : bF;

    #pragma unroll
    for (int it = 0; it < 8; ++it) {
        int idx = it * 256 + tid;
        int jj = idx >> 7, r = idx & 127;
        int g = r >> 5, c5 = r & 31;
        *(u32x4*)(recW + wseg(jj, g, c5) * 8) =
            *(const u32x4*)(Whh + (size_t)(g * 256 + jblk * 16 + jj) * 256 + c5 * 8);
    }
    __syncthreads();

    float bs[4]; f16x8 bx[4];
    #pragma unroll
    for (int g = 0; g < 4; ++g) {
        bs[g] = bias[g * 256 + jblk * 16 + l15];
        bx[g] = *(const f16x8*)(Wih + (size_t)(g * 256 + jblk * 16 + l15) * 32 + q * 8);
    }

    f32x4 creg = { 0.f, 0.f, 0.f, 0.f };

    #pragma unroll 1
    for (int s = 0; s < 512; ++s) {
        int t = dir ? (511 - s) : s;
        {   // wait for partners' h[s] at slot s&3 — one packed 64B flag line
            const int* sp = seq + ((s & 3) * NI + isl) * 16 + (lane & 15);
            for (;;) {
                int ok = 1;
                if (lane < 16) ok = (aload_i(sp) >= s);
                if (__all(ok)) break;
                __builtin_amdgcn_s_sleep(1);
            }
        }
        asm volatile("" ::: "memory");

        // issue all 8 h-frag LLC loads up front (pipelined, vmcnt-only)
        const _Float16* hb = hring + (((size_t)((s & 3) * 2 + dir) * S + strip) * 16) * 1024;
        f16x8 ah[8];
        #pragma unroll
        for (int k0 = 0; k0 < 8; ++k0)
            ah[k0] = gload_h(hb + (size_t)(2 * k0 + (q >> 1)) * 1024 + (wave * 16 + l15) * 16 + (q & 1) * 8);

        f32x4 acc[4];
        #pragma unroll
        for (int g = 0; g < 4; ++g) { f32x4 v = { bs[g], bs[g], bs[g], bs[g] }; acc[g] = v; }

        {   // input term K=32 (overlaps h-load latency)
            f16x8 ax = *(const f16x8*)(xpad + ((size_t)(b0 + strip * 64 + wave * 16 + l15) * 512 + t) * 32 + q * 8);
            #pragma unroll
            for (int g = 0; g < 4; ++g) acc[g] = mfma16(ax, bx[g], acc[g]);
        }
        vmwait8(ah[0], ah[1], ah[2], ah[3], ah[4], ah[5], ah[6], ah[7]);
        #pragma unroll
        for (int k0 = 0; k0 < 8; ++k0) {
            int c5 = k0 * 4 + q;
            #pragma unroll
            for (int g = 0; g < 4; ++g)
                acc[g] = mfma16(ah[k0], *(const f16x8*)(recW + wseg(l15, g, c5) * 8), acc[g]);
        }
        // epilogue
        #pragma unroll
        for (int e = 0; e < 4; ++e) {
            int rl = wave * 16 + q * 4 + e;
            float cn = sigm(acc[1][e]) * creg[e] + sigm(acc[0][e]) * tanh_(acc[2][e]);
            creg[e] = cn;
            hstage[rl * 16 + l15] = (_Float16)(sigm(acc[3][e]) * tanh_(cn));
        }
        __syncthreads();
        u64 pv = ((const u64*)hstage)[tid];
        {   // cooperative coalesced LLC store of own jblk block (2KB)
            _Float16* wb = hring + ((((size_t)(((s + 1) & 3) * 2 + dir) * S + strip) * 16) + jblk) * 1024;
            gstore_u64((u64*)wb + tid, pv);
        }
        asm volatile("s_waitcnt vmcnt(0)" ::: "memory");
        __syncthreads();
        if (tid == 0)
            astore_i(seq + (((s + 1) & 3) * NI + isl) * 16 + jblk, s + 1);
        // out0 store (plain cacheable) — off critical path, after the post
        size_t slab = ((size_t)(t * 16 + jblk) * Bc + strip * 64) * 16;
        if (dir == 0) {
            ((u64*)(out0A + slab))[tid] = pv;                         // f16, 2KB
        } else if (useFp8) {
            union { u64 x; _Float16 h[4]; } cc; cc.x = pv;
            u32 pk = pk_fp8x4((float)cc.h[0] * 16.f, (float)cc.h[1] * 16.f,
                              (float)cc.h[2] * 16.f, (float)cc.h[3] * 16.f);
            *(u32*)(out0B + slab + tid * 4) = pk;                     // fp8, 1KB
        } else {
            ((u64*)((_Float16*)out0B + slab))[tid] = pv;              // f16, 2KB
        }
    }
}

// ---------------- layer 1 merged: each block computes its own G1 slice ----------------
// 32*S blocks (<=256, co-residency guaranteed at 1 block/CU).
// Dynamic LDS 100352B: recW f16 32KB | W1 slice f16 64KB | hstage 2KB.
__global__ __launch_bounds__(256) void l1_merged(
    int S, int sbits, int Bc, int useFp8,
    const _Float16* __restrict__ out0A, const unsigned char* __restrict__ out0B,
    const _Float16* __restrict__ WhhF, const _Float16* __restrict__ WhhB,
    const _Float16* __restrict__ W1F, const _Float16* __restrict__ W1B,
    const float* __restrict__ bF, const float* __restrict__ bB,
    _Float16* __restrict__ hring, int* __restrict__ seq)
{
    extern __shared__ _Float16 dsm[];
    _Float16* recW   = dsm;           // 16384 f16
    _Float16* Wl     = dsm + 16384;   // 32768 f16: [64 gatecols][64 kchunks swz][8]
    _Float16* hstage = dsm + 49152;   // 1024 f16
    int tid = threadIdx.x;
    int wave = tid >> 6, lane = tid & 63, l15 = lane & 15, q = lane >> 4;
    int jblk = blockIdx.x & 15;
    int isl = blockIdx.x >> 4;
    int NI = 2 * S;
    int dir = isl >> sbits, strip = isl & (S - 1);

    const _Float16* Whh = dir ? WhhB : WhhF;
    const _Float16* W1  = dir ? W1B : W1F;
    const float* bias = dir ? bB : bF;

    #pragma unroll
    for (int it = 0; it < 8; ++it) {   // recW
        int idx = it * 256 + tid;
        int jj = idx >> 7, r = idx & 127;
        int g = r >> 5, c5 = r & 31;
        *(u32x4*)(recW + wseg(jj, g, c5) * 8) =
            *(const u32x4*)(Whh + (size_t)(g * 256 + jblk * 16 + jj) * 256 + c5 * 8);
    }
    #pragma unroll
    for (int it = 0; it < 16; ++it) {  // W1 slice: 64 gate-cols (4 gates x 16) of this jblk
        int idx = it * 256 + tid;
        int c = idx >> 6, cc = idx & 63;
        int grow = (c >> 4) * 256 + jblk * 16 + (c & 15);
        *(u32x4*)(Wl + ((size_t)c * 64 + (cc ^ (c & 7))) * 8) =
            *(const u32x4*)(W1 + (size_t)grow * 512 + cc * 8);
    }
    __syncthreads();

    float bs[4];
    #pragma unroll
    for (int g = 0; g < 4; ++g) bs[g] = bias[g * 256 + jblk * 16 + l15];

    f32x4 creg = { 0.f, 0.f, 0.f, 0.f };
    int arow = strip * 64 + wave * 16 + l15;

    #pragma unroll 1
    for (int s = 0; s < 512; ++s) {
        int t = dir ? (511 - s) : s;

        // ---- G1 slice for this step (depends only on out0) — runs pre-poll,
        //      fully hidden under partner-sync latency ----
        // forward half of x1 (k<256): always f16 from out0A
        f16x8 af[8];
        #pragma unroll
        for (int k0 = 0; k0 < 8; ++k0) {
            int jb = 2 * k0 + (q >> 1);
            af[k0] = *(const f16x8*)(out0A + ((size_t)(t * 16 + jb) * Bc + arow) * 16 + (q & 1) * 8);
        }
        // backward half (k>=256): fp8 or f16 from out0B
        u64 cb[8];
        if (useFp8) {
            #pragma unroll
            for (int k0 = 0; k0 < 8; ++k0) {
                int jb = 2 * k0 + (q >> 1);
                cb[k0] = *(const u64*)(out0B + ((size_t)(t * 16 + jb) * Bc + arow) * 16 + (q & 1) * 8);
            }
        } else {
            #pragma unroll
            for (int k0 = 0; k0 < 8; ++k0) {
                int jb = 2 * k0 + (q >> 1);
                cb[k0] = *(const u64*)((const _Float16*)out0B
                    + ((size_t)(t * 16 + jb) * Bc + arow) * 16 + (q & 1) * 8 + (q & 1) * 0);
            }
        }
        f32x4 acc[4];
        #pragma unroll
        for (int g = 0; g < 4; ++g) { f32x4 v = { bs[g], bs[g], bs[g], bs[g] }; acc[g] = v; }
        #pragma unroll
        for (int k0 = 0; k0 < 8; ++k0) {
            int c5 = k0 * 4 + q;
            #pragma unroll
            for (int g = 0; g < 4; ++g) {
                int col = g * 16 + l15;
                f16x8 bb = *(const f16x8*)(Wl + ((size_t)col * 64 + (c5 ^ (col & 7))) * 8);
                acc[g] = mfma16(af[k0], bb, acc[g]);
            }
        }
        if (useFp8) {
            #pragma unroll
            for (int k0 = 0; k0 < 8; ++k0) {
                f16x8 aa = unpk_fp8x8(cb[k0]);
                int c5 = (k0 + 8) * 4 + q;
                #pragma unroll
                for (int g = 0; g < 4; ++g) {
                    int col = g * 16 + l15;
                    f16x8 bb = *(const f16x8*)(Wl + ((size_t)col * 64 + (c5 ^ (col & 7))) * 8);
                    acc[g] = mfma16(aa, bb, acc[g]);
                }
            }
        } else {
            // f16 backward half: need 16B frags — reload as f16x8 (L2-hot, cheap)
            #pragma unroll
            for (int k0 = 0; k0 < 8; ++k0) {
                int jb = 2 * k0 + (q >> 1);
                f16x8 aa = *(const f16x8*)((const _Float16*)out0B
                    + ((size_t)(t * 16 + jb) * Bc + arow) * 16 + (q & 1) * 8);
                int c5 = (k0 + 8) * 4 + q;
                #pragma unroll
                for (int g = 0; g < 4; ++g) {
                    int col = g * 16 + l15;
                    f16x8 bb = *(const f16x8*)(Wl + ((size_t)col * 64 + (c5 ^ (col & 7))) * 8);
                    acc[g] = mfma16(aa, bb, acc[g]);
                }
            }
        }

        {   // wait partners' h[s] — one packed 64B flag line
            const int* sp = seq + ((s & 3) * NI + isl) * 16 + (lane & 15);
            for (;;) {
                int ok = 1;
                if (lane < 16) ok = (aload_i(sp) >= s);
                if (__all(ok)) break;
                __builtin_amdgcn_s_sleep(1);
            }
        }
        asm volatile("" ::: "memory");

        // ---- recurrent term ----
        const _Float16* hb = hring + (((size_t)((s & 3) * 2 + dir) * S + strip) * 16) * 1024;
        f16x8 ah[8];
        #pragma unroll
        for (int k0 = 0; k0 < 8; ++k0)
            ah[k0] = gload_h(hb + (size_t)(2 * k0 + (q >> 1)) * 1024 + (wave * 16 + l15) * 16 + (q & 1) * 8);
        vmwait8(ah[0], ah[1], ah[2], ah[3], ah[4], ah[5], ah[6], ah[7]);
        #pragma unroll
        for (int k0 = 0; k0 < 8; ++k0) {
            int c5 = k0 * 4 + q;
            #pragma unroll
            for (int g = 0; g < 4; ++g)
                acc[g] = mfma16(ah[k0], *(const f16x8*)(recW + wseg(l15, g, c5) * 8), acc[g]);
        }
        // epilogue
        #pragma unroll
        for (int e = 0; e < 4; ++e) {
            int rl = wave * 16 + q * 4 + e;
            float cn = sigm(acc[1][e]) * creg[e] + sigm(acc[0][e]) * tanh_(acc[2][e]);
            creg[e] = cn;
            hstage[rl * 16 + l15] = (_Float16)(sigm(acc[3][e]) * tanh_(cn));
        }
        __syncthreads();
        {
            _Float16* wb = hring + ((((size_t)(((s + 1) & 3) * 2 + dir) * S + strip) * 16) + jblk) * 1024;
            gstore_u64((u64*)wb + tid, ((const u64*)hstage)[tid]);
        }
        asm volatile("s_waitcnt vmcnt(0)" ::: "memory");
        __syncthreads();
        if (tid == 0)
            astore_i(seq + (((s + 1) & 3) * NI + isl) * 16 + jblk, s + 1);
    }
}

// ---------------- final FC ----------------
__global__ __launch_bounds__(64) void fc_kernel(
    int S, const _Float16* __restrict__ hring,
    const float* __restrict__ fcwT, const float* __restrict__ fcb,
    float* __restrict__ out, int b0)
{
    __shared__ float hc[512];
    int b = blockIdx.x, l = threadIdx.x;
    int strip = b >> 6, row = b & 63;
    #pragma unroll
    for (int u = 0; u < 2; ++u) {
        int ui = l * 2 + u;
        int d = ui >> 6, rem = ui & 63;
        int jb = rem >> 2, part = rem & 3;
        const _Float16* hp = hring + (((size_t)d * S + strip) * 16 + jb) * 1024 + row * 16 + part * 4;
        union { u64 x; _Float16 h[4]; } c; c.x = aload_u64(hp);
        #pragma unroll
        for (int k = 0; k < 4; ++k)
            hc[d * 256 + jb * 16 + part * 4 + k] = (float)c.h[k];
    }
    __syncthreads();
    float acc = fcb[l];
    for (int j = 0; j < 512; ++j) acc += hc[j] * fcwT[j * 64 + l];
    out[(b0 + b) * 64 + l] = acc;
}

// ---------------- host ----------------
extern "C" void kernel_launch(void* const* d_in, const int* in_sizes, int n_in,
                              void* d_out, int out_size, void* d_ws, size_t ws_size,
                              hipStream_t stream)
{
    const float* x     = (const float*)d_in[0];
    const float* wih0f = (const float*)d_in[1];
    const float* whh0f = (const float*)d_in[2];
    const float* b0f   = (const float*)d_in[3];
    const float* wih0b = (const float*)d_in[4];
    const float* whh0b = (const float*)d_in[5];
    const float* b0b   = (const float*)d_in[6];
    const float* wih1f = (const float*)d_in[7];
    const float* whh1f = (const float*)d_in[8];
    const float* b1f   = (const float*)d_in[9];
    const float* wih1b = (const float*)d_in[10];
    const float* whh1b = (const float*)d_in[11];
    const float* b1b   = (const float*)d_in[12];
    const float* fcw   = (const float*)d_in[13];
    const float* fcb   = (const float*)d_in[14];
    float* out = (float*)d_out;
    (void)in_sizes; (void)n_in; (void)out_size;

    // workspace ladder: A = Bc512 all-f16 out0, B = Bc512 f16+fp8 split, D = Bc256 all-f16 (nb=2)
    auto totalFor = [](int bc, int f8) -> size_t {
        size_t s = (size_t)bc / 64;
        size_t fixed = 4 * 524288ull + 2 * 65536ull + 2 * 1048576ull
                     + 16777216ull + 131072ull + 4096ull + 65536ull; // + align slack
        return fixed + 262144ull * s
             + 262144ull * (size_t)bc                       // out0A f16
             + (f8 ? 131072ull : 262144ull) * (size_t)bc;   // out0B
    };
    int Bc = 512, useFp8 = 0;
    if (ws_size >= totalFor(512, 0))      { Bc = 512; useFp8 = 0; }
    else if (ws_size >= totalFor(512, 1)) { Bc = 512; useFp8 = 1; }
    else                                  { Bc = 256; useFp8 = 0; }
    while (Bc > 64 && ws_size < totalFor(Bc, useFp8)) Bc >>= 1;  // safety
    const int S = Bc / 64;
    const int nb = 512 / Bc;
    const int sbits = 31 - __builtin_clz((unsigned)S);

    char* pp = (char*)d_ws;
    auto alloc = [&](size_t bytes) -> void* {
        void* r = (void*)pp;
        pp += (bytes + 255) & ~(size_t)255;
        return r;
    };
    _Float16* Whh0f16 = (_Float16*)alloc(524288);
    _Float16* Whh0b16 = (_Float16*)alloc(524288);
    _Float16* Whh1f16 = (_Float16*)alloc(524288);
    _Float16* Whh1b16 = (_Float16*)alloc(524288);
    _Float16* Wih0pf  = (_Float16*)alloc(65536);
    _Float16* Wih0pb  = (_Float16*)alloc(65536);
    _Float16* Wih1f16 = (_Float16*)alloc(1048576);
    _Float16* Wih1b16 = (_Float16*)alloc(1048576);
    _Float16* xpad    = (_Float16*)alloc((size_t)16777216);
    float*    fcwT    = (float*)alloc(131072);
    int*      seqA    = (int*)alloc(4096);
    _Float16* hring   = (_Float16*)alloc((size_t)262144 * S);
    _Float16* out0A   = (_Float16*)alloc((size_t)262144 * Bc);
    unsigned char* out0B = (unsigned char*)alloc((useFp8 ? (size_t)131072 : (size_t)262144) * Bc);

    static int s_attr_done = 0;
    if (!s_attr_done) {
        (void)hipFuncSetAttribute(reinterpret_cast<const void*>(l1_merged),
                                  hipFuncAttributeMaxDynamicSharedMemorySize, 100352);
        s_attr_done = 1;
    }

    cvt_f16s<<<1024, 256, 0, stream>>>(whh0f, Whh0f16, 262144, 1.0f);
    cvt_f16s<<<1024, 256, 0, stream>>>(whh0b, Whh0b16, 262144, 1.0f);
    cvt_f16s<<<1024, 256, 0, stream>>>(whh1f, Whh1f16, 262144, 1.0f);
    cvt_f16s<<<1024, 256, 0, stream>>>(whh1b, Whh1b16, 262144, 1.0f);
    cvt_wih1<<<2048, 256, 0, stream>>>(wih1f, Wih1f16, 524288, useFp8);
    cvt_wih1<<<2048, 256, 0, stream>>>(wih1b, Wih1b16, 524288, useFp8);
    pad_wih0_f16<<<128, 256, 0, stream>>>(wih0f, Wih0pf);
    pad_wih0_f16<<<128, 256, 0, stream>>>(wih0b, Wih0pb);
    pad_x_f16<<<32768, 256, 0, stream>>>(x, xpad);
    transpose_fcw<<<128, 256, 0, stream>>>(fcw, fcwT);

    const size_t seqB   = 4096;
    const size_t hringB = (size_t)262144 * S;

    for (int bchunk = 0; bchunk < nb; ++bchunk) {
        int b0 = bchunk * Bc;

        (void)hipMemsetAsync(seqA, 0, seqB, stream);
        (void)hipMemsetAsync(hring, 0, hringB, stream);
        l0_persist<<<32 * S, 256, 0, stream>>>(S, sbits, Bc, b0, useFp8, xpad,
            Whh0f16, Whh0b16, Wih0pf, Wih0pb, b0f, b0b, hring, seqA, out0A, out0B);

        (void)hipMemsetAsync(seqA, 0, seqB, stream);
        (void)hipMemsetAsync(hring, 0, hringB, stream);
        l1_merged<<<32 * S, 256, 100352, stream>>>(S, sbits, Bc, useFp8, out0A, out0B,
            Whh1f16, Whh1b16, Wih1f16, Wih1b16, b1f, b1b, hring, seqA);

        fc_kernel<<<Bc, 64, 0, stream>>>(S, hring, fcwT, fcb, out, b0);
    }
}

// Round 5
// 4009.602 us; speedup vs baseline: 1.9754x; 1.1018x over previous
//
#include <hip/hip_runtime.h>
#include <stdint.h>

#define DEV static __device__ __forceinline__

typedef float f32x4 __attribute__((ext_vector_type(4)));
typedef float f32x2 __attribute__((ext_vector_type(2)));
typedef unsigned int u32x4 __attribute__((ext_vector_type(4)));
typedef _Float16 f16x8 __attribute__((ext_vector_type(8)));
typedef unsigned long long u64;
typedef unsigned int u32;

DEV float sigm(float x) { return __fdividef(1.0f, 1.0f + __expf(-x)); }
DEV float tanh_(float x) { return 1.0f - __fdividef(2.0f, __expf(2.0f * x) + 1.0f); }

DEV f32x4 mfma16(f16x8 a, f16x8 b, f32x4 c) {
    return __builtin_amdgcn_mfma_f32_16x16x32_f16(a, b, c, 0, 0, 0);
}

// flag ops stay __hip_atomic (R7-validated); poll loops contain no LDS ops so
// flat-op lgkmcnt aliasing cannot serialize anything there.
DEV int aload_i(const int* p) { return __hip_atomic_load(p, __ATOMIC_RELAXED, __HIP_MEMORY_SCOPE_AGENT); }
DEV void astore_i(int* p, int v) { __hip_atomic_store(p, v, __ATOMIC_RELAXED, __HIP_MEMORY_SCOPE_AGENT); }
DEV u64 aload_u64(const void* p) { return __hip_atomic_load((const u64*)p, __ATOMIC_RELAXED, __HIP_MEMORY_SCOPE_AGENT); }

// LLC-coherent (sc0 sc1) vmcnt-only data movement — pipelines, no lgkmcnt alias.
DEV f16x8 gload_h(const _Float16* p) {
    f16x8 v;
    asm volatile("global_load_dwordx4 %0, %1, off sc0 sc1" : "=v"(v) : "v"(p));
    return v;
}
// plain cacheable asm loads (participate in L1/L2) for out0 prefetch
DEV f16x8 gload_c16(const void* p) {
    f16x8 v;
    asm volatile("global_load_dwordx4 %0, %1, off" : "=v"(v) : "v"(p));
    return v;
}
DEV u64 gload_c8(const void* p) {
    u64 v;
    asm volatile("global_load_dwordx2 %0, %1, off" : "=v"(v) : "v"(p));
    return v;
}
DEV void gstore_u64(void* p, u64 v) {
    asm volatile("global_store_dwordx2 %0, %1, off sc0 sc1" :: "v"(p), "v"(v) : "memory");
}
DEV void vmwait8(f16x8& a0, f16x8& a1, f16x8& a2, f16x8& a3,
                 f16x8& a4, f16x8& a5, f16x8& a6, f16x8& a7) {
    asm volatile("s_waitcnt vmcnt(0)"
        : "+v"(a0), "+v"(a1), "+v"(a2), "+v"(a3), "+v"(a4), "+v"(a5), "+v"(a6), "+v"(a7)
        :: "memory");
}
// counted wait: drains only the oldest ops (the 8 h-frag loads [+wave0 flag store]),
// leaving the 16 just-issued out0 prefetch loads in flight across the MFMA phase.
DEV void vmwait8_c16(f16x8& a0, f16x8& a1, f16x8& a2, f16x8& a3,
                     f16x8& a4, f16x8& a5, f16x8& a6, f16x8& a7) {
    asm volatile("s_waitcnt vmcnt(16)"
        : "+v"(a0), "+v"(a1), "+v"(a2), "+v"(a3), "+v"(a4), "+v"(a5), "+v"(a6), "+v"(a7)
        :: "memory");
}

// ---------------- fp8 (E4M3 OCP on gfx950) helpers ----------------
// out0 backward half stores 16*h as fp8; the 1/16 is pre-folded into the
// k>=256 columns of W_ih1 at conversion.
DEV u32 pk_fp8x4(float a, float b, float c, float d) {
    int v = __builtin_amdgcn_cvt_pk_fp8_f32(a, b, 0, false);
    v = __builtin_amdgcn_cvt_pk_fp8_f32(c, d, v, true);
    return (u32)v;
}
DEV f16x8 unpk_fp8x8(u64 w) {
    u32 w0 = (u32)w, w1 = (u32)(w >> 32);
    f32x2 p0 = __builtin_amdgcn_cvt_pk_f32_fp8((int)w0, false);
    f32x2 p1 = __builtin_amdgcn_cvt_pk_f32_fp8((int)w0, true);
    f32x2 p2 = __builtin_amdgcn_cvt_pk_f32_fp8((int)w1, false);
    f32x2 p3 = __builtin_amdgcn_cvt_pk_f32_fp8((int)w1, true);
    f16x8 r;
    r[0] = (_Float16)p0[0]; r[1] = (_Float16)p0[1];
    r[2] = (_Float16)p1[0]; r[3] = (_Float16)p1[1];
    r[4] = (_Float16)p2[0]; r[5] = (_Float16)p2[1];
    r[6] = (_Float16)p3[0]; r[7] = (_Float16)p3[1];
    return r;
}

// ---------------- packing pre-passes ----------------
__global__ __launch_bounds__(256) void cvt_f16s(const float* __restrict__ src, _Float16* __restrict__ dst, int n, float sc) {
    int o = blockIdx.x * 256 + threadIdx.x;
    if (o < n) dst[o] = (_Float16)(src[o] * sc);
}
// W_ih1: scale k>=256 columns by 1/16 only when backward half of x1 is fp8 (16x pre-scale)
__global__ __launch_bounds__(256) void cvt_wih1(const float* __restrict__ src, _Float16* __restrict__ dst, int n, int fp8half) {
    int o = blockIdx.x * 256 + threadIdx.x;
    if (o < n) {
        float sc = (fp8half && ((o & 511) >= 256)) ? 0.0625f : 1.0f;
        dst[o] = (_Float16)(src[o] * sc);
    }
}
__global__ __launch_bounds__(256) void pad_wih0_f16(const float* __restrict__ src, _Float16* __restrict__ dst) {
    int o = blockIdx.x * 256 + threadIdx.x;   // 32768
    int k = o & 31, r = o >> 5;
    dst[o] = (k < 16) ? (_Float16)src[r * 16 + k] : (_Float16)0.f;
}
__global__ __launch_bounds__(256) void pad_x_f16(const float* __restrict__ src, _Float16* __restrict__ dst) {
    int o = blockIdx.x * 256 + threadIdx.x;   // 8388608
    int k = o & 31;
    int t = (o >> 5) & 511;
    int b = o >> 14;
    dst[o] = (k < 16) ? (_Float16)src[((size_t)b * 512 + t) * 16 + k] : (_Float16)0.f;
}
__global__ __launch_bounds__(256) void transpose_fcw(const float* __restrict__ src, float* __restrict__ dst) {
    int o = blockIdx.x * 256 + threadIdx.x;   // 32768
    int j = o >> 6, l = o & 63;
    dst[o] = src[l * 512 + j];
}

// LDS W slice: 16B segment index for (jj in [0,16), gate, c5 = k0*4+q), XOR swizzle
DEV int wseg(int jj, int g, int c5) { return jj * 128 + g * 32 + (c5 ^ (jj & 7)); }

// ---------------- layer 0 persistent (dataflow-sync) ----------------
// XCD grouping: isl = bid & (NI-1), jblk = bid >> (sbits+1) -> bid%8 = isl%8, so
// the 16 jblk partners of one isl share an XCD (xpad reads L2-shared).
// out0A (dir0, f16): [t][jblk][row Bc][16]. out0B (dir1): f16 same layout or fp8 (scale 16).
__global__ __launch_bounds__(256) void l0_persist(
    int S, int sbits, int Bc, int b0, int useFp8,
    const _Float16* __restrict__ xpad,
    const _Float16* __restrict__ WhhF, const _Float16* __restrict__ WhhB,
    const _Float16* __restrict__ WihF, const _Float16* __restrict__ WihB,
    const float* __restrict__ bF, const float* __restrict__ bB,
    _Float16* __restrict__ hring, int* __restrict__ seq,
    _Float16* __restrict__ out0A, unsigned char* __restrict__ out0B)
{
    __shared__ _Float16 recW[16384];   // 32KB
    __shared__ _Float16 hstage[1024];  // 2KB
    int tid = threadIdx.x;
    int wave = tid >> 6, lane = tid & 63, l15 = lane & 15, q = lane >> 4;
    int NI = 2 * S;
    int isl = blockIdx.x & (NI - 1);
    int jblk = blockIdx.x >> (sbits + 1);
    int dir = isl >> sbits, strip = isl & (S - 1);

    const _Float16* Whh = dir ? WhhB : WhhF;
    const _Float16* Wih = dir ? WihB : WihF;
    const float* bias = dir ? bB : bF;

    #pragma unroll
    for (int it = 0; it < 8; ++it) {
        int idx = it * 256 + tid;
        int jj = idx >> 7, r = idx & 127;
        int g = r >> 5, c5 = r & 31;
        *(u32x4*)(recW + wseg(jj, g, c5) * 8) =
            *(const u32x4*)(Whh + (size_t)(g * 256 + jblk * 16 + jj) * 256 + c5 * 8);
    }
    __syncthreads();

    float bs[4]; f16x8 bx[4];
    #pragma unroll
    for (int g = 0; g < 4; ++g) {
        bs[g] = bias[g * 256 + jblk * 16 + l15];
        bx[g] = *(const f16x8*)(Wih + (size_t)(g * 256 + jblk * 16 + l15) * 32 + q * 8);
    }

    f32x4 creg = { 0.f, 0.f, 0.f, 0.f };

    #pragma unroll 1
    for (int s = 0; s < 512; ++s) {
        int t = dir ? (511 - s) : s;
        {   // wait for partners' h[s] at slot s&3 — one packed 64B flag line
            const int* sp = seq + ((s & 3) * NI + isl) * 16 + (lane & 15);
            for (;;) {
                int ok = 1;
                if (lane < 16) ok = (aload_i(sp) >= s);
                if (__all(ok)) break;
                __builtin_amdgcn_s_sleep(1);
            }
        }
        asm volatile("" ::: "memory");

        // issue all 8 h-frag LLC loads up front (pipelined, vmcnt-only)
        const _Float16* hb = hring + (((size_t)((s & 3) * 2 + dir) * S + strip) * 16) * 1024;
        f16x8 ah[8];
        #pragma unroll
        for (int k0 = 0; k0 < 8; ++k0)
            ah[k0] = gload_h(hb + (size_t)(2 * k0 + (q >> 1)) * 1024 + (wave * 16 + l15) * 16 + (q & 1) * 8);

        f32x4 acc[4];
        #pragma unroll
        for (int g = 0; g < 4; ++g) { f32x4 v = { bs[g], bs[g], bs[g], bs[g] }; acc[g] = v; }

        {   // input term K=32 (overlaps h-load latency)
            f16x8 ax = *(const f16x8*)(xpad + ((size_t)(b0 + strip * 64 + wave * 16 + l15) * 512 + t) * 32 + q * 8);
            #pragma unroll
            for (int g = 0; g < 4; ++g) acc[g] = mfma16(ax, bx[g], acc[g]);
        }
        vmwait8(ah[0], ah[1], ah[2], ah[3], ah[4], ah[5], ah[6], ah[7]);
        #pragma unroll
        for (int k0 = 0; k0 < 8; ++k0) {
            int c5 = k0 * 4 + q;
            #pragma unroll
            for (int g = 0; g < 4; ++g)
                acc[g] = mfma16(ah[k0], *(const f16x8*)(recW + wseg(l15, g, c5) * 8), acc[g]);
        }
        // epilogue
        #pragma unroll
        for (int e = 0; e < 4; ++e) {
            int rl = wave * 16 + q * 4 + e;
            float cn = sigm(acc[1][e]) * creg[e] + sigm(acc[0][e]) * tanh_(acc[2][e]);
            creg[e] = cn;
            hstage[rl * 16 + l15] = (_Float16)(sigm(acc[3][e]) * tanh_(cn));
        }
        __syncthreads();
        u64 pv = ((const u64*)hstage)[tid];
        {   // cooperative coalesced LLC store of own jblk block (2KB)
            _Float16* wb = hring + ((((size_t)(((s + 1) & 3) * 2 + dir) * S + strip) * 16) + jblk) * 1024;
            gstore_u64((u64*)wb + tid, pv);
        }
        asm volatile("s_waitcnt vmcnt(0)" ::: "memory");
        __syncthreads();
        if (tid == 0)
            astore_i(seq + (((s + 1) & 3) * NI + isl) * 16 + jblk, s + 1);
        // out0 store (plain cacheable) — off critical path, after the post
        size_t slab = ((size_t)(t * 16 + jblk) * Bc + strip * 64) * 16;
        if (dir == 0) {
            ((u64*)(out0A + slab))[tid] = pv;                         // f16, 2KB
        } else if (useFp8) {
            union { u64 x; _Float16 h[4]; } cc; cc.x = pv;
            u32 pk = pk_fp8x4((float)cc.h[0] * 16.f, (float)cc.h[1] * 16.f,
                              (float)cc.h[2] * 16.f, (float)cc.h[3] * 16.f);
            *(u32*)(out0B + slab + tid * 4) = pk;                     // fp8, 1KB
        } else {
            ((u64*)((_Float16*)out0B + slab))[tid] = pv;              // f16, 2KB
        }
    }
}

// ---------------- layer 1 merged, G1 prefetch-pipelined ----------------
// 32*S blocks, 1/CU. Per step: poll -> issue 8 h LLC loads -> G1 MFMAs from
// prefetched regs (hides h latency) -> issue next-step out0 prefetch (16 loads)
// -> counted vmcnt(16) (drains h only) -> recurrent MFMAs -> epilogue.
// End-of-step vmcnt(0) drain is the prefetch completion fence for next iter.
template<int FP8>
__global__ __launch_bounds__(256) void l1_merged_t(
    int S, int sbits, int Bc,
    const _Float16* __restrict__ out0A, const unsigned char* __restrict__ out0B,
    const _Float16* __restrict__ WhhF, const _Float16* __restrict__ WhhB,
    const _Float16* __restrict__ W1F, const _Float16* __restrict__ W1B,
    const float* __restrict__ bF, const float* __restrict__ bB,
    _Float16* __restrict__ hring, int* __restrict__ seq)
{
    extern __shared__ _Float16 dsm[];
    _Float16* recW   = dsm;           // 16384 f16
    _Float16* Wl     = dsm + 16384;   // 32768 f16: [64 gatecols][64 kchunks swz][8]
    _Float16* hstage = dsm + 49152;   // 1024 f16
    int tid = threadIdx.x;
    int wave = tid >> 6, lane = tid & 63, l15 = lane & 15, q = lane >> 4;
    int NI = 2 * S;
    int isl = blockIdx.x & (NI - 1);          // XCD-group: partners share bid%8
    int jblk = blockIdx.x >> (sbits + 1);
    int dir = isl >> sbits, strip = isl & (S - 1);

    const _Float16* Whh = dir ? WhhB : WhhF;
    const _Float16* W1  = dir ? W1B : W1F;
    const float* bias = dir ? bB : bF;

    #pragma unroll
    for (int it = 0; it < 8; ++it) {   // recW
        int idx = it * 256 + tid;
        int jj = idx >> 7, r = idx & 127;
        int g = r >> 5, c5 = r & 31;
        *(u32x4*)(recW + wseg(jj, g, c5) * 8) =
            *(const u32x4*)(Whh + (size_t)(g * 256 + jblk * 16 + jj) * 256 + c5 * 8);
    }
    #pragma unroll
    for (int it = 0; it < 16; ++it) {  // W1 slice: 64 gate-cols (4 gates x 16) of this jblk
        int idx = it * 256 + tid;
        int c = idx >> 6, cc = idx & 63;
        int grow = (c >> 4) * 256 + jblk * 16 + (c & 15);
        *(u32x4*)(Wl + ((size_t)c * 64 + (cc ^ (c & 7))) * 8) =
            *(const u32x4*)(W1 + (size_t)grow * 512 + cc * 8);
    }
    __syncthreads();

    float bs[4];
    #pragma unroll
    for (int g = 0; g < 4; ++g) bs[g] = bias[g * 256 + jblk * 16 + l15];

    f32x4 creg = { 0.f, 0.f, 0.f, 0.f };
    int arow = strip * 64 + wave * 16 + l15;

    // persistent prefetch registers; prologue fill for s=0 (compiler loads, waited at use)
    f16x8 af[8]; u64 cb[8]; f16x8 ab[8];
    {
        int tp = dir ? 511 : 0;
        #pragma unroll
        for (int k0 = 0; k0 < 8; ++k0) {
            int jb = 2 * k0 + (q >> 1);
            size_t off = ((size_t)(tp * 16 + jb) * Bc + arow) * 16 + (q & 1) * 8;
            af[k0] = *(const f16x8*)(out0A + off);
            if (FP8) cb[k0] = *(const u64*)(out0B + off);
            else     ab[k0] = *(const f16x8*)((const _Float16*)out0B + off);
        }
    }

    #pragma unroll 1
    for (int s = 0; s < 512; ++s) {
        {   // wait partners' h[s] — one packed 64B flag line
            const int* sp = seq + ((s & 3) * NI + isl) * 16 + (lane & 15);
            for (;;) {
                int ok = 1;
                if (lane < 16) ok = (aload_i(sp) >= s);
                if (__all(ok)) break;
                __builtin_amdgcn_s_sleep(1);
            }
        }
        asm volatile("" ::: "memory");

        // issue 8 h-frag LLC loads first (their latency is hidden by G1 MFMAs below)
        const _Float16* hb = hring + (((size_t)((s & 3) * 2 + dir) * S + strip) * 16) * 1024;
        f16x8 ah[8];
        #pragma unroll
        for (int k0 = 0; k0 < 8; ++k0)
            ah[k0] = gload_h(hb + (size_t)(2 * k0 + (q >> 1)) * 1024 + (wave * 16 + l15) * 16 + (q & 1) * 8);

        // G1 slice from prefetched registers
        f32x4 acc[4];
        #pragma unroll
        for (int g = 0; g < 4; ++g) { f32x4 v = { bs[g], bs[g], bs[g], bs[g] }; acc[g] = v; }
        #pragma unroll
        for (int k0 = 0; k0 < 8; ++k0) {
            int c5 = k0 * 4 + q;
            #pragma unroll
            for (int g = 0; g < 4; ++g) {
                int col = g * 16 + l15;
                f16x8 bb = *(const f16x8*)(Wl + ((size_t)col * 64 + (c5 ^ (col & 7))) * 8);
                acc[g] = mfma16(af[k0], bb, acc[g]);
            }
        }
        #pragma unroll
        for (int k0 = 0; k0 < 8; ++k0) {
            f16x8 aa;
            if (FP8) aa = unpk_fp8x8(cb[k0]);
            else     aa = ab[k0];
            int c5 = (k0 + 8) * 4 + q;
            #pragma unroll
            for (int g = 0; g < 4; ++g) {
                int col = g * 16 + l15;
                f16x8 bb = *(const f16x8*)(Wl + ((size_t)col * 64 + (c5 ^ (col & 7))) * 8);
                acc[g] = mfma16(aa, bb, acc[g]);
            }
        }

        // prefetch next step's out0 frags (16 asm loads, stay in flight past vmcnt(16))
        {
            int tn = (dir ? (510 - s) : (s + 1)) & 511;   // clamped at s=511 (data unused)
            #pragma unroll
            for (int k0 = 0; k0 < 8; ++k0) {
                int jb = 2 * k0 + (q >> 1);
                size_t off = ((size_t)(tn * 16 + jb) * Bc + arow) * 16 + (q & 1) * 8;
                af[k0] = gload_c16(out0A + off);
                if (FP8) cb[k0] = gload_c8(out0B + off);
                else     ab[k0] = gload_c16((const _Float16*)out0B + off);
            }
        }

        // counted wait: completes the 8 h loads (+wave0 flag store), keeps prefetch in flight
        vmwait8_c16(ah[0], ah[1], ah[2], ah[3], ah[4], ah[5], ah[6], ah[7]);

        #pragma unroll
        for (int k0 = 0; k0 < 8; ++k0) {
            int c5 = k0 * 4 + q;
            #pragma unroll
            for (int g = 0; g < 4; ++g)
                acc[g] = mfma16(ah[k0], *(const f16x8*)(recW + wseg(l15, g, c5) * 8), acc[g]);
        }
        // epilogue
        #pragma unroll
        for (int e = 0; e < 4; ++e) {
            int rl = wave * 16 + q * 4 + e;
            float cn = sigm(acc[1][e]) * creg[e] + sigm(acc[0][e]) * tanh_(acc[2][e]);
            creg[e] = cn;
            hstage[rl * 16 + l15] = (_Float16)(sigm(acc[3][e]) * tanh_(cn));
        }
        __syncthreads();
        {
            _Float16* wb = hring + ((((size_t)(((s + 1) & 3) * 2 + dir) * S + strip) * 16) + jblk) * 1024;
            gstore_u64((u64*)wb + tid, ((const u64*)hstage)[tid]);
        }
        // drains h-store AND the out0 prefetch -> next iter's G1 reads are valid
        asm volatile("s_waitcnt vmcnt(0)" ::: "memory");
        __syncthreads();
        if (tid == 0)
            astore_i(seq + (((s + 1) & 3) * NI + isl) * 16 + jblk, s + 1);
    }
}

// ---------------- final FC ----------------
__global__ __launch_bounds__(64) void fc_kernel(
    int S, const _Float16* __restrict__ hring,
    const float* __restrict__ fcwT, const float* __restrict__ fcb,
    float* __restrict__ out, int b0)
{
    __shared__ float hc[512];
    int b = blockIdx.x, l = threadIdx.x;
    int strip = b >> 6, row = b & 63;
    #pragma unroll
    for (int u = 0; u < 2; ++u) {
        int ui = l * 2 + u;
        int d = ui >> 6, rem = ui & 63;
        int jb = rem >> 2, part = rem & 3;
        const _Float16* hp = hring + (((size_t)d * S + strip) * 16 + jb) * 1024 + row * 16 + part * 4;
        union { u64 x; _Float16 h[4]; } c; c.x = aload_u64(hp);
        #pragma unroll
        for (int k = 0; k < 4; ++k)
            hc[d * 256 + jb * 16 + part * 4 + k] = (float)c.h[k];
    }
    __syncthreads();
    float acc = fcb[l];
    for (int j = 0; j < 512; ++j) acc += hc[j] * fcwT[j * 64 + l];
    out[(b0 + b) * 64 + l] = acc;
}

// ---------------- host ----------------
extern "C" void kernel_launch(void* const* d_in, const int* in_sizes, int n_in,
                              void* d_out, int out_size, void* d_ws, size_t ws_size,
                              hipStream_t stream)
{
    const float* x     = (const float*)d_in[0];
    const float* wih0f = (const float*)d_in[1];
    const float* whh0f = (const float*)d_in[2];
    const float* b0f   = (const float*)d_in[3];
    const float* wih0b = (const float*)d_in[4];
    const float* whh0b = (const float*)d_in[5];
    const float* b0b   = (const float*)d_in[6];
    const float* wih1f = (const float*)d_in[7];
    const float* whh1f = (const float*)d_in[8];
    const float* b1f   = (const float*)d_in[9];
    const float* wih1b = (const float*)d_in[10];
    const float* whh1b = (const float*)d_in[11];
    const float* b1b   = (const float*)d_in[12];
    const float* fcw   = (const float*)d_in[13];
    const float* fcb   = (const float*)d_in[14];
    float* out = (float*)d_out;
    (void)in_sizes; (void)n_in; (void)out_size;

    // workspace ladder: A = Bc512 all-f16 out0, B = Bc512 f16+fp8 split, D = Bc256 all-f16 (nb=2)
    auto totalFor = [](int bc, int f8) -> size_t {
        size_t s = (size_t)bc / 64;
        size_t fixed = 4 * 524288ull + 2 * 65536ull + 2 * 1048576ull
                     + 16777216ull + 131072ull + 4096ull + 65536ull; // + align slack
        return fixed + 262144ull * s
             + 262144ull * (size_t)bc                       // out0A f16
             + (f8 ? 131072ull : 262144ull) * (size_t)bc;   // out0B
    };
    int Bc = 512, useFp8 = 0;
    if (ws_size >= totalFor(512, 0))      { Bc = 512; useFp8 = 0; }
    else if (ws_size >= totalFor(512, 1)) { Bc = 512; useFp8 = 1; }
    else                                  { Bc = 256; useFp8 = 0; }
    while (Bc > 64 && ws_size < totalFor(Bc, useFp8)) Bc >>= 1;  // safety
    const int S = Bc / 64;
    const int nb = 512 / Bc;
    const int sbits = 31 - __builtin_clz((unsigned)S);

    char* pp = (char*)d_ws;
    auto alloc = [&](size_t bytes) -> void* {
        void* r = (void*)pp;
        pp += (bytes + 255) & ~(size_t)255;
        return r;
    };
    _Float16* Whh0f16 = (_Float16*)alloc(524288);
    _Float16* Whh0b16 = (_Float16*)alloc(524288);
    _Float16* Whh1f16 = (_Float16*)alloc(524288);
    _Float16* Whh1b16 = (_Float16*)alloc(524288);
    _Float16* Wih0pf  = (_Float16*)alloc(65536);
    _Float16* Wih0pb  = (_Float16*)alloc(65536);
    _Float16* Wih1f16 = (_Float16*)alloc(1048576);
    _Float16* Wih1b16 = (_Float16*)alloc(1048576);
    _Float16* xpad    = (_Float16*)alloc((size_t)16777216);
    float*    fcwT    = (float*)alloc(131072);
    int*      seqA    = (int*)alloc(4096);
    _Float16* hring   = (_Float16*)alloc((size_t)262144 * S);
    _Float16* out0A   = (_Float16*)alloc((size_t)262144 * Bc);
    unsigned char* out0B = (unsigned char*)alloc((useFp8 ? (size_t)131072 : (size_t)262144) * Bc);

    static int s_attr_done = 0;
    if (!s_attr_done) {
        (void)hipFuncSetAttribute(reinterpret_cast<const void*>(&l1_merged_t<0>),
                                  hipFuncAttributeMaxDynamicSharedMemorySize, 100352);
        (void)hipFuncSetAttribute(reinterpret_cast<const void*>(&l1_merged_t<1>),
                                  hipFuncAttributeMaxDynamicSharedMemorySize, 100352);
        s_attr_done = 1;
    }

    cvt_f16s<<<1024, 256, 0, stream>>>(whh0f, Whh0f16, 262144, 1.0f);
    cvt_f16s<<<1024, 256, 0, stream>>>(whh0b, Whh0b16, 262144, 1.0f);
    cvt_f16s<<<1024, 256, 0, stream>>>(whh1f, Whh1f16, 262144, 1.0f);
    cvt_f16s<<<1024, 256, 0, stream>>>(whh1b, Whh1b16, 262144, 1.0f);
    cvt_wih1<<<2048, 256, 0, stream>>>(wih1f, Wih1f16, 524288, useFp8);
    cvt_wih1<<<2048, 256, 0, stream>>>(wih1b, Wih1b16, 524288, useFp8);
    pad_wih0_f16<<<128, 256, 0, stream>>>(wih0f, Wih0pf);
    pad_wih0_f16<<<128, 256, 0, stream>>>(wih0b, Wih0pb);
    pad_x_f16<<<32768, 256, 0, stream>>>(x, xpad);
    transpose_fcw<<<128, 256, 0, stream>>>(fcw, fcwT);

    const size_t seqB   = 4096;
    const size_t hringB = (size_t)262144 * S;

    for (int bchunk = 0; bchunk < nb; ++bchunk) {
        int b0 = bchunk * Bc;

        (void)hipMemsetAsync(seqA, 0, seqB, stream);
        (void)hipMemsetAsync(hring, 0, hringB, stream);
        l0_persist<<<32 * S, 256, 0, stream>>>(S, sbits, Bc, b0, useFp8, xpad,
            Whh0f16, Whh0b16, Wih0pf, Wih0pb, b0f, b0b, hring, seqA, out0A, out0B);

        (void)hipMemsetAsync(seqA, 0, seqB, stream);
        (void)hipMemsetAsync(hring, 0, hringB, stream);
        if (useFp8)
            l1_merged_t<1><<<32 * S, 256, 100352, stream>>>(S, sbits, Bc, out0A, out0B,
                Whh1f16, Whh1b16, Wih1f16, Wih1b16, b1f, b1b, hring, seqA);
        else
            l1_merged_t<0><<<32 * S, 256, 100352, stream>>>(S, sbits, Bc, out0A, out0B,
                Whh1f16, Whh1b16, Wih1f16, Wih1b16, b1f, b1b, hring, seqA);

        fc_kernel<<<Bc, 64, 0, stream>>>(S, hring, fcwT, fcb, out, b0);
    }
}

// Round 7
// 3820.155 us; speedup vs baseline: 2.0734x; 1.0496x over previous
//
#include <hip/hip_runtime.h>
#include <stdint.h>

#define DEV static __device__ __forceinline__

typedef float f32x4 __attribute__((ext_vector_type(4)));
typedef float f32x2 __attribute__((ext_vector_type(2)));
typedef unsigned int u32x4 __attribute__((ext_vector_type(4)));
typedef _Float16 f16x8 __attribute__((ext_vector_type(8)));
typedef unsigned long long u64;
typedef unsigned int u32;

DEV float sigm(float x) { return __fdividef(1.0f, 1.0f + __expf(-x)); }
DEV float tanh_(float x) { return 1.0f - __fdividef(2.0f, __expf(2.0f * x) + 1.0f); }

DEV f32x4 mfma16(f16x8 a, f16x8 b, f32x4 c) {
    return __builtin_amdgcn_mfma_f32_16x16x32_f16(a, b, c, 0, 0, 0);
}

// flag ops: agent-scope atomics (proven). Poll loops contain no LDS ops.
DEV int aload_i(const int* p) { return __hip_atomic_load(p, __ATOMIC_RELAXED, __HIP_MEMORY_SCOPE_AGENT); }
DEV void astore_i(int* p, int v) { __hip_atomic_store(p, v, __ATOMIC_RELAXED, __HIP_MEMORY_SCOPE_AGENT); }
DEV u64 aload_u64(const void* p) { return __hip_atomic_load((const u64*)p, __ATOMIC_RELAXED, __HIP_MEMORY_SCOPE_AGENT); }

// LLC-coherent (sc0 sc1) vmcnt-only data movement — pipelines, no lgkmcnt alias.
DEV f16x8 gload_h(const _Float16* p) {
    f16x8 v;
    asm volatile("global_load_dwordx4 %0, %1, off sc0 sc1" : "=v"(v) : "v"(p));
    return v;
}
// plain cacheable asm loads (participate in L1/L2) for out0 prefetch
DEV f16x8 gload_c16(const void* p) {
    f16x8 v;
    asm volatile("global_load_dwordx4 %0, %1, off" : "=v"(v) : "v"(p));
    return v;
}
DEV u64 gload_c8(const void* p) {
    u64 v;
    asm volatile("global_load_dwordx2 %0, %1, off" : "=v"(v) : "v"(p));
    return v;
}
DEV void gstore_u64(void* p, u64 v) {
    asm volatile("global_store_dwordx2 %0, %1, off sc0 sc1" :: "v"(p), "v"(v) : "memory");
}
DEV void vmwait8(f16x8& a0, f16x8& a1, f16x8& a2, f16x8& a3,
                 f16x8& a4, f16x8& a5, f16x8& a6, f16x8& a7) {
    asm volatile("s_waitcnt vmcnt(0)"
        : "+v"(a0), "+v"(a1), "+v"(a2), "+v"(a3), "+v"(a4), "+v"(a5), "+v"(a6), "+v"(a7)
        :: "memory");
}
// prefetch-completion fences at step top: register-tied so MFMAs can't hoist above (rule #18)
DEV void vmwait_pf_fp8(f16x8& a0, f16x8& a1, f16x8& a2, f16x8& a3,
                       f16x8& a4, f16x8& a5, f16x8& a6, f16x8& a7,
                       u64& c0, u64& c1, u64& c2, u64& c3,
                       u64& c4, u64& c5, u64& c6, u64& c7) {
    asm volatile("s_waitcnt vmcnt(0)"
        : "+v"(a0), "+v"(a1), "+v"(a2), "+v"(a3), "+v"(a4), "+v"(a5), "+v"(a6), "+v"(a7),
          "+v"(c0), "+v"(c1), "+v"(c2), "+v"(c3), "+v"(c4), "+v"(c5), "+v"(c6), "+v"(c7)
        :: "memory");
}
DEV void vmwait_pf_f16(f16x8& a0, f16x8& a1, f16x8& a2, f16x8& a3,
                       f16x8& a4, f16x8& a5, f16x8& a6, f16x8& a7,
                       f16x8& b0, f16x8& b1, f16x8& b2, f16x8& b3,
                       f16x8& b4, f16x8& b5, f16x8& b6, f16x8& b7) {
    asm volatile("s_waitcnt vmcnt(0)"
        : "+v"(a0), "+v"(a1), "+v"(a2), "+v"(a3), "+v"(a4), "+v"(a5), "+v"(a6), "+v"(a7),
          "+v"(b0), "+v"(b1), "+v"(b2), "+v"(b3), "+v"(b4), "+v"(b5), "+v"(b6), "+v"(b7)
        :: "memory");
}

// ---------------- fp8 (E4M3 OCP on gfx950) helpers ----------------
// out0 backward half stores 16*h as fp8; the 1/16 is pre-folded into the
// k>=256 columns of W_ih1 at conversion.
DEV u32 pk_fp8x4(float a, float b, float c, float d) {
    int v = __builtin_amdgcn_cvt_pk_fp8_f32(a, b, 0, false);
    v = __builtin_amdgcn_cvt_pk_fp8_f32(c, d, v, true);
    return (u32)v;
}
DEV f16x8 unpk_fp8x8(u64 w) {
    u32 w0 = (u32)w, w1 = (u32)(w >> 32);
    f32x2 p0 = __builtin_amdgcn_cvt_pk_f32_fp8((int)w0, false);
    f32x2 p1 = __builtin_amdgcn_cvt_pk_f32_fp8((int)w0, true);
    f32x2 p2 = __builtin_amdgcn_cvt_pk_f32_fp8((int)w1, false);
    f32x2 p3 = __builtin_amdgcn_cvt_pk_f32_fp8((int)w1, true);
    f16x8 r;
    r[0] = (_Float16)p0[0]; r[1] = (_Float16)p0[1];
    r[2] = (_Float16)p1[0]; r[3] = (_Float16)p1[1];
    r[4] = (_Float16)p2[0]; r[5] = (_Float16)p2[1];
    r[6] = (_Float16)p3[0]; r[7] = (_Float16)p3[1];
    return r;
}

// ---------------- packing pre-passes ----------------
__global__ __launch_bounds__(256) void cvt_f16s(const float* __restrict__ src, _Float16* __restrict__ dst, int n, float sc) {
    int o = blockIdx.x * 256 + threadIdx.x;
    if (o < n) dst[o] = (_Float16)(src[o] * sc);
}
__global__ __launch_bounds__(256) void cvt_wih1(const float* __restrict__ src, _Float16* __restrict__ dst, int n, int fp8half) {
    int o = blockIdx.x * 256 + threadIdx.x;
    if (o < n) {
        float sc = (fp8half && ((o & 511) >= 256)) ? 0.0625f : 1.0f;
        dst[o] = (_Float16)(src[o] * sc);
    }
}
__global__ __launch_bounds__(256) void pad_wih0_f16(const float* __restrict__ src, _Float16* __restrict__ dst) {
    int o = blockIdx.x * 256 + threadIdx.x;   // 32768
    int k = o & 31, r = o >> 5;
    dst[o] = (k < 16) ? (_Float16)src[r * 16 + k] : (_Float16)0.f;
}
__global__ __launch_bounds__(256) void pad_x_f16(const float* __restrict__ src, _Float16* __restrict__ dst) {
    int o = blockIdx.x * 256 + threadIdx.x;   // 8388608
    int k = o & 31;
    int t = (o >> 5) & 511;
    int b = o >> 14;
    dst[o] = (k < 16) ? (_Float16)src[((size_t)b * 512 + t) * 16 + k] : (_Float16)0.f;
}
__global__ __launch_bounds__(256) void transpose_fcw(const float* __restrict__ src, float* __restrict__ dst) {
    int o = blockIdx.x * 256 + threadIdx.x;   // 32768
    int j = o >> 6, l = o & 63;
    dst[o] = src[l * 512 + j];
}

// LDS W slice: 16B segment index for (jj in [0,16), gate, c5 = k0*4+q), XOR swizzle
DEV int wseg(int jj, int g, int c5) { return jj * 128 + g * 32 + (c5 ^ (jj & 7)); }

// ---------------- layer 0 persistent (dataflow-sync) ----------------
// XCD grouping: isl = bid & (NI-1), jblk = bid >> (sbits+1) -> bid%8 = isl%8, so
// the 16 jblk partners of one isl share an XCD (xpad/out0 reads L2-shared).
// out0A (dir0, f16): [t][jblk][row Bc][16]. out0B (dir1): f16 same layout or fp8 (scale 16).
__global__ __launch_bounds__(256) void l0_persist(
    int S, int sbits, int Bc, int b0, int useFp8,
    const _Float16* __restrict__ xpad,
    const _Float16* __restrict__ WhhF, const _Float16* __restrict__ WhhB,
    const _Float16* __restrict__ WihF, const _Float16* __restrict__ WihB,
    const float* __restrict__ bF, const float* __restrict__ bB,
    _Float16* __restrict__ hring, int* __restrict__ seq,
    _Float16* __restrict__ out0A, unsigned char* __restrict__ out0B)
{
    __shared__ _Float16 recW[16384];   // 32KB
    __shared__ _Float16 hstage[1024];  // 2KB
    int tid = threadIdx.x;
    int wave = tid >> 6, lane = tid & 63, l15 = lane & 15, q = lane >> 4;
    int NI = 2 * S;
    int isl = blockIdx.x & (NI - 1);
    int jblk = blockIdx.x >> (sbits + 1);
    int dir = isl >> sbits, strip = isl & (S - 1);

    const _Float16* Whh = dir ? WhhB : WhhF;
    const _Float16* Wih = dir ? WihB : WihF;
    const float* bias = dir ? bB : bF;

    #pragma unroll
    for (int it = 0; it < 8; ++it) {
        int idx = it * 256 + tid;
        int jj = idx >> 7, r = idx & 127;
        int g = r >> 5, c5 = r & 31;
        *(u32x4*)(recW + wseg(jj, g, c5) * 8) =
            *(const u32x4*)(Whh + (size_t)(g * 256 + jblk * 16 + jj) * 256 + c5 * 8);
    }
    __syncthreads();

    float bs[4]; f16x8 bx[4];
    #pragma unroll
    for (int g = 0; g < 4; ++g) {
        bs[g] = bias[g * 256 + jblk * 16 + l15];
        bx[g] = *(const f16x8*)(Wih + (size_t)(g * 256 + jblk * 16 + l15) * 32 + q * 8);
    }

    f32x4 creg = { 0.f, 0.f, 0.f, 0.f };

    #pragma unroll 1
    for (int s = 0; s < 512; ++s) {
        int t = dir ? (511 - s) : s;
        {   // wait for partners' h[s] at slot s&3 — one packed 64B flag line
            const int* sp = seq + ((s & 3) * NI + isl) * 16 + (lane & 15);
            for (;;) {
                int ok = 1;
                if (lane < 16) ok = (aload_i(sp) >= s);
                if (__all(ok)) break;
                __builtin_amdgcn_s_sleep(1);
            }
        }
        asm volatile("" ::: "memory");

        // issue all 8 h-frag LLC loads up front (pipelined, vmcnt-only)
        const _Float16* hb = hring + (((size_t)((s & 3) * 2 + dir) * S + strip) * 16) * 1024;
        f16x8 ah[8];
        #pragma unroll
        for (int k0 = 0; k0 < 8; ++k0)
            ah[k0] = gload_h(hb + (size_t)(2 * k0 + (q >> 1)) * 1024 + (wave * 16 + l15) * 16 + (q & 1) * 8);

        f32x4 acc[4];
        #pragma unroll
        for (int g = 0; g < 4; ++g) { f32x4 v = { bs[g], bs[g], bs[g], bs[g] }; acc[g] = v; }

        {   // input term K=32 (overlaps h-load latency)
            f16x8 ax = *(const f16x8*)(xpad + ((size_t)(b0 + strip * 64 + wave * 16 + l15) * 512 + t) * 32 + q * 8);
            #pragma unroll
            for (int g = 0; g < 4; ++g) acc[g] = mfma16(ax, bx[g], acc[g]);
        }
        vmwait8(ah[0], ah[1], ah[2], ah[3], ah[4], ah[5], ah[6], ah[7]);
        #pragma unroll
        for (int k0 = 0; k0 < 8; ++k0) {
            int c5 = k0 * 4 + q;
            #pragma unroll
            for (int g = 0; g < 4; ++g)
                acc[g] = mfma16(ah[k0], *(const f16x8*)(recW + wseg(l15, g, c5) * 8), acc[g]);
        }
        // epilogue
        #pragma unroll
        for (int e = 0; e < 4; ++e) {
            int rl = wave * 16 + q * 4 + e;
            float cn = sigm(acc[1][e]) * creg[e] + sigm(acc[0][e]) * tanh_(acc[2][e]);
            creg[e] = cn;
            hstage[rl * 16 + l15] = (_Float16)(sigm(acc[3][e]) * tanh_(cn));
        }
        __syncthreads();
        u64 pv = ((const u64*)hstage)[tid];
        {   // cooperative coalesced LLC store of own jblk block (2KB)
            _Float16* wb = hring + ((((size_t)(((s + 1) & 3) * 2 + dir) * S + strip) * 16) + jblk) * 1024;
            gstore_u64((u64*)wb + tid, pv);
        }
        asm volatile("s_waitcnt vmcnt(0)" ::: "memory");
        __syncthreads();
        if (tid == 0)
            astore_i(seq + (((s + 1) & 3) * NI + isl) * 16 + jblk, s + 1);
        // out0 store (plain cacheable) — off critical path, after the post
        size_t slab = ((size_t)(t * 16 + jblk) * Bc + strip * 64) * 16;
        if (dir == 0) {
            ((u64*)(out0A + slab))[tid] = pv;                         // f16, 2KB
        } else if (useFp8) {
            union { u64 x; _Float16 h[4]; } cc; cc.x = pv;
            u32 pk = pk_fp8x4((float)cc.h[0] * 16.f, (float)cc.h[1] * 16.f,
                              (float)cc.h[2] * 16.f, (float)cc.h[3] * 16.f);
            *(u32*)(out0B + slab + tid * 4) = pk;                     // fp8, 1KB
        } else {
            ((u64*)((_Float16*)out0B + slab))[tid] = pv;              // f16, 2KB
        }
    }
}

// ---------------- layer 1 merged, G1 prefetch-pipelined (post-first ordering) ----------------
// Per step: poll -> vmwait_pf (prefetched out0 regs valid) -> issue 8 h loads ->
// G1 MFMAs (hide h latency) -> vmcnt(0) -> rec MFMAs -> epilogue -> h-store ->
// vmcnt(0) (store only!) -> flag post -> THEN issue next-step out0 prefetch.
// The flag post is never gated by prefetch drain; all waits are exact vmcnt(0).
template<int FP8>
__global__ __launch_bounds__(256) void l1_merged_t(
    int S, int sbits, int Bc,
    const _Float16* __restrict__ out0A, const unsigned char* __restrict__ out0B,
    const _Float16* __restrict__ WhhF, const _Float16* __restrict__ WhhB,
    const _Float16* __restrict__ W1F, const _Float16* __restrict__ W1B,
    const float* __restrict__ bF, const float* __restrict__ bB,
    _Float16* __restrict__ hring, int* __restrict__ seq)
{
    extern __shared__ _Float16 dsm[];
    _Float16* recW   = dsm;           // 16384 f16
    _Float16* Wl     = dsm + 16384;   // 32768 f16: [64 gatecols][64 kchunks swz][8]
    _Float16* hstage = dsm + 49152;   // 1024 f16
    int tid = threadIdx.x;
    int wave = tid >> 6, lane = tid & 63, l15 = lane & 15, q = lane >> 4;
    int NI = 2 * S;
    int isl = blockIdx.x & (NI - 1);          // XCD-group: partners share bid%8
    int jblk = blockIdx.x >> (sbits + 1);
    int dir = isl >> sbits, strip = isl & (S - 1);

    const _Float16* Whh = dir ? WhhB : WhhF;
    const _Float16* W1  = dir ? W1B : W1F;
    const float* bias = dir ? bB : bF;

    #pragma unroll
    for (int it = 0; it < 8; ++it) {   // recW
        int idx = it * 256 + tid;
        int jj = idx >> 7, r = idx & 127;
        int g = r >> 5, c5 = r & 31;
        *(u32x4*)(recW + wseg(jj, g, c5) * 8) =
            *(const u32x4*)(Whh + (size_t)(g * 256 + jblk * 16 + jj) * 256 + c5 * 8);
    }
    #pragma unroll
    for (int it = 0; it < 16; ++it) {  // W1 slice: 64 gate-cols (4 gates x 16) of this jblk
        int idx = it * 256 + tid;
        int c = idx >> 6, cc = idx & 63;
        int grow = (c >> 4) * 256 + jblk * 16 + (c & 15);
        *(u32x4*)(Wl + ((size_t)c * 64 + (cc ^ (c & 7))) * 8) =
            *(const u32x4*)(W1 + (size_t)grow * 512 + cc * 8);
    }
    __syncthreads();

    float bs[4];
    #pragma unroll
    for (int g = 0; g < 4; ++g) bs[g] = bias[g * 256 + jblk * 16 + l15];

    f32x4 creg = { 0.f, 0.f, 0.f, 0.f };
    int arow = strip * 64 + wave * 16 + l15;

    // persistent prefetch registers; prologue fill for s=0 (compiler loads, waited at use)
    f16x8 af[8]; u64 cb[8]; f16x8 ab[8];
    {
        int tp = dir ? 511 : 0;
        #pragma unroll
        for (int k0 = 0; k0 < 8; ++k0) {
            int jb = 2 * k0 + (q >> 1);
            size_t off = ((size_t)(tp * 16 + jb) * Bc + arow) * 16 + (q & 1) * 8;
            af[k0] = *(const f16x8*)(out0A + off);
            if (FP8) cb[k0] = *(const u64*)(out0B + off);
            else     ab[k0] = *(const f16x8*)((const _Float16*)out0B + off);
        }
    }

    #pragma unroll 1
    for (int s = 0; s < 512; ++s) {
        {   // wait partners' h[s] — one packed 64B flag line
            const int* sp = seq + ((s & 3) * NI + isl) * 16 + (lane & 15);
            for (;;) {
                int ok = 1;
                if (lane < 16) ok = (aload_i(sp) >= s);
                if (__all(ok)) break;
                __builtin_amdgcn_s_sleep(1);
            }
        }
        asm volatile("" ::: "memory");

        // prefetch regs valid beyond this point (register-tied fence)
        if (FP8) vmwait_pf_fp8(af[0], af[1], af[2], af[3], af[4], af[5], af[6], af[7],
                               cb[0], cb[1], cb[2], cb[3], cb[4], cb[5], cb[6], cb[7]);
        else     vmwait_pf_f16(af[0], af[1], af[2], af[3], af[4], af[5], af[6], af[7],
                               ab[0], ab[1], ab[2], ab[3], ab[4], ab[5], ab[6], ab[7]);

        // issue 8 h-frag LLC loads first (their latency is hidden by G1 MFMAs below)
        const _Float16* hb = hring + (((size_t)((s & 3) * 2 + dir) * S + strip) * 16) * 1024;
        f16x8 ah[8];
        #pragma unroll
        for (int k0 = 0; k0 < 8; ++k0)
            ah[k0] = gload_h(hb + (size_t)(2 * k0 + (q >> 1)) * 1024 + (wave * 16 + l15) * 16 + (q & 1) * 8);

        // G1 slice from prefetched registers
        f32x4 acc[4];
        #pragma unroll
        for (int g = 0; g < 4; ++g) { f32x4 v = { bs[g], bs[g], bs[g], bs[g] }; acc[g] = v; }
        #pragma unroll
        for (int k0 = 0; k0 < 8; ++k0) {
            int c5 = k0 * 4 + q;
            #pragma unroll
            for (int g = 0; g < 4; ++g) {
                int col = g * 16 + l15;
                f16x8 bb = *(const f16x8*)(Wl + ((size_t)col * 64 + (c5 ^ (col & 7))) * 8);
                acc[g] = mfma16(af[k0], bb, acc[g]);
            }
        }
        #pragma unroll
        for (int k0 = 0; k0 < 8; ++k0) {
            f16x8 aa;
            if (FP8) aa = unpk_fp8x8(cb[k0]);
            else     aa = ab[k0];
            int c5 = (k0 + 8) * 4 + q;
            #pragma unroll
            for (int g = 0; g < 4; ++g) {
                int col = g * 16 + l15;
                f16x8 bb = *(const f16x8*)(Wl + ((size_t)col * 64 + (c5 ^ (col & 7))) * 8);
                acc[g] = mfma16(aa, bb, acc[g]);
            }
        }

        // exact drain: only the 8 h loads are outstanding here
        vmwait8(ah[0], ah[1], ah[2], ah[3], ah[4], ah[5], ah[6], ah[7]);

        #pragma unroll
        for (int k0 = 0; k0 < 8; ++k0) {
            int c5 = k0 * 4 + q;
            #pragma unroll
            for (int g = 0; g < 4; ++g)
                acc[g] = mfma16(ah[k0], *(const f16x8*)(recW + wseg(l15, g, c5) * 8), acc[g]);
        }
        // epilogue
        #pragma unroll
        for (int e = 0; e < 4; ++e) {
            int rl = wave * 16 + q * 4 + e;
            float cn = sigm(acc[1][e]) * creg[e] + sigm(acc[0][e]) * tanh_(acc[2][e]);
            creg[e] = cn;
            hstage[rl * 16 + l15] = (_Float16)(sigm(acc[3][e]) * tanh_(cn));
        }
        __syncthreads();
        {
            _Float16* wb = hring + ((((size_t)(((s + 1) & 3) * 2 + dir) * S + strip) * 16) + jblk) * 1024;
            gstore_u64((u64*)wb + tid, ((const u64*)hstage)[tid]);
        }
        // drains only the h-store (prefetch not yet issued) — fast flag post
        asm volatile("s_waitcnt vmcnt(0)" ::: "memory");
        __syncthreads();
        if (tid == 0)
            astore_i(seq + (((s + 1) & 3) * NI + isl) * 16 + jblk, s + 1);

        // NOW issue next step's out0 prefetch (16 loads) — flies during next poll
        {
            int tn = (dir ? (510 - s) : (s + 1)) & 511;   // clamped at s=511 (data unused)
            #pragma unroll
            for (int k0 = 0; k0 < 8; ++k0) {
                int jb = 2 * k0 + (q >> 1);
                size_t off = ((size_t)(tn * 16 + jb) * Bc + arow) * 16 + (q & 1) * 8;
                af[k0] = gload_c16(out0A + off);
                if (FP8) cb[k0] = gload_c8(out0B + off);
                else     ab[k0] = gload_c16((const _Float16*)out0B + off);
            }
        }
    }
}

// ---------------- final FC ----------------
__global__ __launch_bounds__(64) void fc_kernel(
    int S, const _Float16* __restrict__ hring,
    const float* __restrict__ fcwT, const float* __restrict__ fcb,
    float* __restrict__ out, int b0)
{
    __shared__ float hc[512];
    int b = blockIdx.x, l = threadIdx.x;
    int strip = b >> 6, row = b & 63;
    #pragma unroll
    for (int u = 0; u < 2; ++u) {
        int ui = l * 2 + u;
        int d = ui >> 6, rem = ui & 63;
        int jb = rem >> 2, part = rem & 3;
        const _Float16* hp = hring + (((size_t)d * S + strip) * 16 + jb) * 1024 + row * 16 + part * 4;
        union { u64 x; _Float16 h[4]; } c; c.x = aload_u64(hp);
        #pragma unroll
        for (int k = 0; k < 4; ++k)
            hc[d * 256 + jb * 16 + part * 4 + k] = (float)c.h[k];
    }
    __syncthreads();
    float acc = fcb[l];
    for (int j = 0; j < 512; ++j) acc += hc[j] * fcwT[j * 64 + l];
    out[(b0 + b) * 64 + l] = acc;
}

// ---------------- host ----------------
extern "C" void kernel_launch(void* const* d_in, const int* in_sizes, int n_in,
                              void* d_out, int out_size, void* d_ws, size_t ws_size,
                              hipStream_t stream)
{
    const float* x     = (const float*)d_in[0];
    const float* wih0f = (const float*)d_in[1];
    const float* whh0f = (const float*)d_in[2];
    const float* b0f   = (const float*)d_in[3];
    const float* wih0b = (const float*)d_in[4];
    const float* whh0b = (const float*)d_in[5];
    const float* b0b   = (const float*)d_in[6];
    const float* wih1f = (const float*)d_in[7];
    const float* whh1f = (const float*)d_in[8];
    const float* b1f   = (const float*)d_in[9];
    const float* wih1b = (const float*)d_in[10];
    const float* whh1b = (const float*)d_in[11];
    const float* b1b   = (const float*)d_in[12];
    const float* fcw   = (const float*)d_in[13];
    const float* fcb   = (const float*)d_in[14];
    float* out = (float*)d_out;
    (void)in_sizes; (void)n_in; (void)out_size;

    // workspace ladder: A = Bc512 all-f16 out0, B = Bc512 f16+fp8 split, D = Bc256 all-f16 (nb=2)
    auto totalFor = [](int bc, int f8) -> size_t {
        size_t s = (size_t)bc / 64;
        size_t fixed = 4 * 524288ull + 2 * 65536ull + 2 * 1048576ull
                     + 16777216ull + 131072ull + 4096ull + 65536ull; // + align slack
        return fixed + 262144ull * s
             + 262144ull * (size_t)bc                       // out0A f16
             + (f8 ? 131072ull : 262144ull) * (size_t)bc;   // out0B
    };
    int Bc = 512, useFp8 = 0;
    if (ws_size >= totalFor(512, 0))      { Bc = 512; useFp8 = 0; }
    else if (ws_size >= totalFor(512, 1)) { Bc = 512; useFp8 = 1; }
    else                                  { Bc = 256; useFp8 = 0; }
    while (Bc > 64 && ws_size < totalFor(Bc, useFp8)) Bc >>= 1;  // safety
    const int S = Bc / 64;
    const int nb = 512 / Bc;
    const int sbits = 31 - __builtin_clz((unsigned)S);

    char* pp = (char*)d_ws;
    auto alloc = [&](size_t bytes) -> void* {
        void* r = (void*)pp;
        pp += (bytes + 255) & ~(size_t)255;
        return r;
    };
    _Float16* Whh0f16 = (_Float16*)alloc(524288);
    _Float16* Whh0b16 = (_Float16*)alloc(524288);
    _Float16* Whh1f16 = (_Float16*)alloc(524288);
    _Float16* Whh1b16 = (_Float16*)alloc(524288);
    _Float16* Wih0pf  = (_Float16*)alloc(65536);
    _Float16* Wih0pb  = (_Float16*)alloc(65536);
    _Float16* Wih1f16 = (_Float16*)alloc(1048576);
    _Float16* Wih1b16 = (_Float16*)alloc(1048576);
    _Float16* xpad    = (_Float16*)alloc((size_t)16777216);
    float*    fcwT    = (float*)alloc(131072);
    int*      seqA    = (int*)alloc(4096);
    _Float16* hring   = (_Float16*)alloc((size_t)262144 * S);
    _Float16* out0A   = (_Float16*)alloc((size_t)262144 * Bc);
    unsigned char* out0B = (unsigned char*)alloc((useFp8 ? (size_t)131072 : (size_t)262144) * Bc);

    static int s_attr_done = 0;
    if (!s_attr_done) {
        (void)hipFuncSetAttribute(reinterpret_cast<const void*>(&l1_merged_t<0>),
                                  hipFuncAttributeMaxDynamicSharedMemorySize, 100352);
        (void)hipFuncSetAttribute(reinterpret_cast<const void*>(&l1_merged_t<1>),
                                  hipFuncAttributeMaxDynamicSharedMemorySize, 100352);
        s_attr_done = 1;
    }

    cvt_f16s<<<1024, 256, 0, stream>>>(whh0f, Whh0f16, 262144, 1.0f);
    cvt_f16s<<<1024, 256, 0, stream>>>(whh0b, Whh0b16, 262144, 1.0f);
    cvt_f16s<<<1024, 256, 0, stream>>>(whh1f, Whh1f16, 262144, 1.0f);
    cvt_f16s<<<1024, 256, 0, stream>>>(whh1b, Whh1b16, 262144, 1.0f);
    cvt_wih1<<<2048, 256, 0, stream>>>(wih1f, Wih1f16, 524288, useFp8);
    cvt_wih1<<<2048, 256, 0, stream>>>(wih1b, Wih1b16, 524288, useFp8);
    pad_wih0_f16<<<128, 256, 0, stream>>>(wih0f, Wih0pf);
    pad_wih0_f16<<<128, 256, 0, stream>>>(wih0b, Wih0pb);
    pad_x_f16<<<32768, 256, 0, stream>>>(x, xpad);
    transpose_fcw<<<128, 256, 0, stream>>>(fcw, fcwT);

    const size_t seqB   = 4096;
    const size_t hringB = (size_t)262144 * S;

    for (int bchunk = 0; bchunk < nb; ++bchunk) {
        int b0 = bchunk * Bc;

        (void)hipMemsetAsync(seqA, 0, seqB, stream);
        (void)hipMemsetAsync(hring, 0, hringB, stream);
        l0_persist<<<32 * S, 256, 0, stream>>>(S, sbits, Bc, b0, useFp8, xpad,
            Whh0f16, Whh0b16, Wih0pf, Wih0pb, b0f, b0b, hring, seqA, out0A, out0B);

        (void)hipMemsetAsync(seqA, 0, seqB, stream);
        (void)hipMemsetAsync(hring, 0, hringB, stream);
        if (useFp8)
            l1_merged_t<1><<<32 * S, 256, 100352, stream>>>(S, sbits, Bc, out0A, out0B,
                Whh1f16, Whh1b16, Wih1f16, Wih1b16, b1f, b1b, hring, seqA);
        else
            l1_merged_t<0><<<32 * S, 256, 100352, stream>>>(S, sbits, Bc, out0A, out0B,
                Whh1f16, Whh1b16, Wih1f16, Wih1b16, b1f, b1b, hring, seqA);

        fc_kernel<<<Bc, 64, 0, stream>>>(S, hring, fcwT, fcb, out, b0);
    }
}

// Round 10
// 3596.691 us; speedup vs baseline: 2.2022x; 1.0621x over previous
//
#include <hip/hip_runtime.h>
#include <stdint.h>

#define DEV static __device__ __forceinline__

typedef float f32x4 __attribute__((ext_vector_type(4)));
typedef float f32x2 __attribute__((ext_vector_type(2)));
typedef unsigned int u32x4 __attribute__((ext_vector_type(4)));
typedef _Float16 f16x8 __attribute__((ext_vector_type(8)));
typedef unsigned long long u64;
typedef unsigned int u32;

DEV float sigm(float x) { return __fdividef(1.0f, 1.0f + __expf(-x)); }
DEV float tanh_(float x) { return 1.0f - __fdividef(2.0f, __expf(2.0f * x) + 1.0f); }

DEV f32x4 mfma16(f16x8 a, f16x8 b, f32x4 c) {
    return __builtin_amdgcn_mfma_f32_16x16x32_f16(a, b, c, 0, 0, 0);
}

// flag ops: agent-scope atomics (proven). Poll loops contain no LDS ops.
DEV int aload_i(const int* p) { return __hip_atomic_load(p, __ATOMIC_RELAXED, __HIP_MEMORY_SCOPE_AGENT); }
DEV void astore_i(int* p, int v) { __hip_atomic_store(p, v, __ATOMIC_RELAXED, __HIP_MEMORY_SCOPE_AGENT); }
DEV u64 aload_u64(const void* p) { return __hip_atomic_load((const u64*)p, __ATOMIC_RELAXED, __HIP_MEMORY_SCOPE_AGENT); }

// LLC-coherent (sc0 sc1) vmcnt-only data movement — pipelines, no lgkmcnt alias.
DEV f16x8 gload_h(const _Float16* p) {
    f16x8 v;
    asm volatile("global_load_dwordx4 %0, %1, off sc0 sc1" : "=v"(v) : "v"(p));
    return v;
}
// plain cacheable asm loads (participate in L1/L2) for register prefetch
DEV f16x8 gload_c16(const void* p) {
    f16x8 v;
    asm volatile("global_load_dwordx4 %0, %1, off" : "=v"(v) : "v"(p));
    return v;
}
DEV u64 gload_c8(const void* p) {
    u64 v;
    asm volatile("global_load_dwordx2 %0, %1, off" : "=v"(v) : "v"(p));
    return v;
}
DEV void gstore_u64(void* p, u64 v) {
    asm volatile("global_store_dwordx2 %0, %1, off sc0 sc1" :: "v"(p), "v"(v) : "memory");
}
DEV void vmwait8(f16x8& a0, f16x8& a1, f16x8& a2, f16x8& a3,
                 f16x8& a4, f16x8& a5, f16x8& a6, f16x8& a7) {
    asm volatile("s_waitcnt vmcnt(0)"
        : "+v"(a0), "+v"(a1), "+v"(a2), "+v"(a3), "+v"(a4), "+v"(a5), "+v"(a6), "+v"(a7)
        :: "memory");
}
// ax-prefetch fence (l0): placed right after the poll (vmcnt already 0 there),
// BEFORE the h-loads are issued — over-drains nothing; ties axr (rule #18).
DEV void vmwait_ax(f16x8& a) {
    asm volatile("s_waitcnt vmcnt(0)" : "+v"(a) :: "memory");
}
// prefetch-completion fences at l1 step top: register-tied so MFMAs can't hoist above
DEV void vmwait_pf_fp8(f16x8& a0, f16x8& a1, f16x8& a2, f16x8& a3,
                       f16x8& a4, f16x8& a5, f16x8& a6, f16x8& a7,
                       u64& c0, u64& c1, u64& c2, u64& c3,
                       u64& c4, u64& c5, u64& c6, u64& c7) {
    asm volatile("s_waitcnt vmcnt(0)"
        : "+v"(a0), "+v"(a1), "+v"(a2), "+v"(a3), "+v"(a4), "+v"(a5), "+v"(a6), "+v"(a7),
          "+v"(c0), "+v"(c1), "+v"(c2), "+v"(c3), "+v"(c4), "+v"(c5), "+v"(c6), "+v"(c7)
        :: "memory");
}
DEV void vmwait_pf_f16(f16x8& a0, f16x8& a1, f16x8& a2, f16x8& a3,
                       f16x8& a4, f16x8& a5, f16x8& a6, f16x8& a7,
                       f16x8& b0, f16x8& b1, f16x8& b2, f16x8& b3,
                       f16x8& b4, f16x8& b5, f16x8& b6, f16x8& b7) {
    asm volatile("s_waitcnt vmcnt(0)"
        : "+v"(a0), "+v"(a1), "+v"(a2), "+v"(a3), "+v"(a4), "+v"(a5), "+v"(a6), "+v"(a7),
          "+v"(b0), "+v"(b1), "+v"(b2), "+v"(b3), "+v"(b4), "+v"(b5), "+v"(b6), "+v"(b7)
        :: "memory");
}

// ---------------- fp8 (E4M3 OCP on gfx950) helpers ----------------
// out0 backward half stores 16*h as fp8; the 1/16 is pre-folded into the
// k>=256 columns of W_ih1 at conversion.
DEV u32 pk_fp8x4(float a, float b, float c, float d) {
    int v = __builtin_amdgcn_cvt_pk_fp8_f32(a, b, 0, false);
    v = __builtin_amdgcn_cvt_pk_fp8_f32(c, d, v, true);
    return (u32)v;
}
DEV f16x8 unpk_fp8x8(u64 w) {
    u32 w0 = (u32)w, w1 = (u32)(w >> 32);
    f32x2 p0 = __builtin_amdgcn_cvt_pk_f32_fp8((int)w0, false);
    f32x2 p1 = __builtin_amdgcn_cvt_pk_f32_fp8((int)w0, true);
    f32x2 p2 = __builtin_amdgcn_cvt_pk_f32_fp8((int)w1, false);
    f32x2 p3 = __builtin_amdgcn_cvt_pk_f32_fp8((int)w1, true);
    f16x8 r;
    r[0] = (_Float16)p0[0]; r[1] = (_Float16)p0[1];
    r[2] = (_Float16)p1[0]; r[3] = (_Float16)p1[1];
    r[4] = (_Float16)p2[0]; r[5] = (_Float16)p2[1];
    r[6] = (_Float16)p3[0]; r[7] = (_Float16)p3[1];
    return r;
}

// ---------------- packing pre-passes ----------------
__global__ __launch_bounds__(256) void cvt_f16s(const float* __restrict__ src, _Float16* __restrict__ dst, int n, float sc) {
    int o = blockIdx.x * 256 + threadIdx.x;
    if (o < n) dst[o] = (_Float16)(src[o] * sc);
}
__global__ __launch_bounds__(256) void cvt_wih1(const float* __restrict__ src, _Float16* __restrict__ dst, int n, int fp8half) {
    int o = blockIdx.x * 256 + threadIdx.x;
    if (o < n) {
        float sc = (fp8half && ((o & 511) >= 256)) ? 0.0625f : 1.0f;
        dst[o] = (_Float16)(src[o] * sc);
    }
}
__global__ __launch_bounds__(256) void pad_wih0_f16(const float* __restrict__ src, _Float16* __restrict__ dst) {
    int o = blockIdx.x * 256 + threadIdx.x;   // 32768
    int k = o & 31, r = o >> 5;
    dst[o] = (k < 16) ? (_Float16)src[r * 16 + k] : (_Float16)0.f;
}
__global__ __launch_bounds__(256) void pad_x_f16(const float* __restrict__ src, _Float16* __restrict__ dst) {
    int o = blockIdx.x * 256 + threadIdx.x;   // 8388608
    int k = o & 31;
    int t = (o >> 5) & 511;
    int b = o >> 14;
    dst[o] = (k < 16) ? (_Float16)src[((size_t)b * 512 + t) * 16 + k] : (_Float16)0.f;
}
__global__ __launch_bounds__(256) void transpose_fcw(const float* __restrict__ src, float* __restrict__ dst) {
    int o = blockIdx.x * 256 + threadIdx.x;   // 32768
    int j = o >> 6, l = o & 63;
    dst[o] = src[l * 512 + j];
}

// LDS W slice: 16B segment index for (jj in [0,16), gate, c5 = k0*4+q), XOR swizzle
DEV int wseg(int jj, int g, int c5) { return jj * 128 + g * 32 + (c5 ^ (jj & 7)); }

// ---------------- layer 0 persistent (dataflow-sync) ----------------
// XCD grouping: isl = bid & (NI-1), jblk = bid >> (sbits+1) -> bid%8 = isl%8, so
// the 16 jblk partners of one isl share an XCD (xpad/out0 reads L2-shared).
// out0A (dir0, f16): [t][jblk][row Bc][16]. out0B (dir1): f16 same layout or fp8 (scale 16).
// ax (x-input frag) is REGISTER-PREFETCHED one step ahead: prefetch issued after the
// flag post (lands during next poll); waited by vmwait_ax right after the poll, BEFORE
// the h-loads are issued — so the 4 x-MFMAs run waitcnt-free and cover h-load latency.
__global__ __launch_bounds__(256) void l0_persist(
    int S, int sbits, int Bc, int b0, int useFp8,
    const _Float16* __restrict__ xpad,
    const _Float16* __restrict__ WhhF, const _Float16* __restrict__ WhhB,
    const _Float16* __restrict__ WihF, const _Float16* __restrict__ WihB,
    const float* __restrict__ bF, const float* __restrict__ bB,
    _Float16* __restrict__ hring, int* __restrict__ seq,
    _Float16* __restrict__ out0A, unsigned char* __restrict__ out0B)
{
    __shared__ _Float16 recW[16384];   // 32KB
    __shared__ _Float16 hstage[1024];  // 2KB
    int tid = threadIdx.x;
    int wave = tid >> 6, lane = tid & 63, l15 = lane & 15, q = lane >> 4;
    int NI = 2 * S;
    int isl = blockIdx.x & (NI - 1);
    int jblk = blockIdx.x >> (sbits + 1);
    int dir = isl >> sbits, strip = isl & (S - 1);

    const _Float16* Whh = dir ? WhhB : WhhF;
    const _Float16* Wih = dir ? WihB : WihF;
    const float* bias = dir ? bB : bF;

    #pragma unroll
    for (int it = 0; it < 8; ++it) {
        int idx = it * 256 + tid;
        int jj = idx >> 7, r = idx & 127;
        int g = r >> 5, c5 = r & 31;
        *(u32x4*)(recW + wseg(jj, g, c5) * 8) =
            *(const u32x4*)(Whh + (size_t)(g * 256 + jblk * 16 + jj) * 256 + c5 * 8);
    }
    __syncthreads();

    float bs[4]; f16x8 bx[4];
    #pragma unroll
    for (int g = 0; g < 4; ++g) {
        bs[g] = bias[g * 256 + jblk * 16 + l15];
        bx[g] = *(const f16x8*)(Wih + (size_t)(g * 256 + jblk * 16 + l15) * 32 + q * 8);
    }

    f32x4 creg = { 0.f, 0.f, 0.f, 0.f };
    const size_t xrow = ((size_t)(b0 + strip * 64 + wave * 16 + l15) * 512) * 32 + q * 8;

    // prologue ax fill for s=0 (plain compiler load; compiler inserts its own wait)
    f16x8 axr = *(const f16x8*)(xpad + xrow + (size_t)(dir ? 511 : 0) * 32);

    #pragma unroll 1
    for (int s = 0; s < 512; ++s) {
        int t = dir ? (511 - s) : s;
        {   // wait for partners' h[s] at slot s&3 — one packed 64B flag line
            const int* sp = seq + ((s & 3) * NI + isl) * 16 + (lane & 15);
            for (;;) {
                int ok = 1;
                if (lane < 16) ok = (aload_i(sp) >= s);
                if (__all(ok)) break;
                __builtin_amdgcn_s_sleep(1);
            }
        }
        asm volatile("" ::: "memory");
        // ax prefetch landed during the poll; tie it now (vmcnt already ~0 here,
        // and the 8 h-loads are NOT yet issued, so this over-drains nothing)
        vmwait_ax(axr);

        // issue all 8 h-frag LLC loads up front (pipelined, vmcnt-only)
        const _Float16* hb = hring + (((size_t)((s & 3) * 2 + dir) * S + strip) * 16) * 1024;
        f16x8 ah[8];
        #pragma unroll
        for (int k0 = 0; k0 < 8; ++k0)
            ah[k0] = gload_h(hb + (size_t)(2 * k0 + (q >> 1)) * 1024 + (wave * 16 + l15) * 16 + (q & 1) * 8);

        f32x4 acc[4];
        #pragma unroll
        for (int g = 0; g < 4; ++g) { f32x4 v = { bs[g], bs[g], bs[g], bs[g] }; acc[g] = v; }

        {   // input term K=32 from REGISTERS — no waitcnt, genuinely overlaps h latency
            #pragma unroll
            for (int g = 0; g < 4; ++g) acc[g] = mfma16(axr, bx[g], acc[g]);
        }
        vmwait8(ah[0], ah[1], ah[2], ah[3], ah[4], ah[5], ah[6], ah[7]);
        #pragma unroll
        for (int k0 = 0; k0 < 8; ++k0) {
            int c5 = k0 * 4 + q;
            #pragma unroll
            for (int g = 0; g < 4; ++g)
                acc[g] = mfma16(ah[k0], *(const f16x8*)(recW + wseg(l15, g, c5) * 8), acc[g]);
        }
        // epilogue
        #pragma unroll
        for (int e = 0; e < 4; ++e) {
            int rl = wave * 16 + q * 4 + e;
            float cn = sigm(acc[1][e]) * creg[e] + sigm(acc[0][e]) * tanh_(acc[2][e]);
            creg[e] = cn;
            hstage[rl * 16 + l15] = (_Float16)(sigm(acc[3][e]) * tanh_(cn));
        }
        __syncthreads();
        u64 pv = ((const u64*)hstage)[tid];
        {   // cooperative coalesced LLC store of own jblk block (2KB)
            _Float16* wb = hring + ((((size_t)(((s + 1) & 3) * 2 + dir) * S + strip) * 16) + jblk) * 1024;
            gstore_u64((u64*)wb + tid, pv);
        }
        asm volatile("s_waitcnt vmcnt(0)" ::: "memory");
        __syncthreads();
        if (tid == 0)
            astore_i(seq + (((s + 1) & 3) * NI + isl) * 16 + jblk, s + 1);
        // out0 store (plain cacheable) — off critical path, after the post
        size_t slab = ((size_t)(t * 16 + jblk) * Bc + strip * 64) * 16;
        if (dir == 0) {
            ((u64*)(out0A + slab))[tid] = pv;                         // f16, 2KB
        } else if (useFp8) {
            union { u64 x; _Float16 h[4]; } cc; cc.x = pv;
            u32 pk = pk_fp8x4((float)cc.h[0] * 16.f, (float)cc.h[1] * 16.f,
                              (float)cc.h[2] * 16.f, (float)cc.h[3] * 16.f);
            *(u32*)(out0B + slab + tid * 4) = pk;                     // fp8, 1KB
        } else {
            ((u64*)((_Float16*)out0B + slab))[tid] = pv;              // f16, 2KB
        }
        // issue next step's ax prefetch — lands during the next poll
        {
            int tn = (dir ? (510 - s) : (s + 1)) & 511;   // clamped at s=511 (data unused)
            axr = gload_c16(xpad + xrow + (size_t)tn * 32);
        }
    }
}

// ---------------- layer 1 merged, G1 prefetch-pipelined (post-first ordering) ----------------
// Per step: poll -> vmwait_pf (prefetched out0 regs valid) -> issue 8 h loads ->
// G1 MFMAs (hide h latency) -> vmcnt(0) -> rec MFMAs -> epilogue -> h-store ->
// vmcnt(0) (store only!) -> flag post -> THEN issue next-step out0 prefetch.
// The flag post is never gated by prefetch drain; all waits are exact vmcnt(0).
template<int FP8>
__global__ __launch_bounds__(256) void l1_merged_t(
    int S, int sbits, int Bc,
    const _Float16* __restrict__ out0A, const unsigned char* __restrict__ out0B,
    const _Float16* __restrict__ WhhF, const _Float16* __restrict__ WhhB,
    const _Float16* __restrict__ W1F, const _Float16* __restrict__ W1B,
    const float* __restrict__ bF, const float* __restrict__ bB,
    _Float16* __restrict__ hring, int* __restrict__ seq)
{
    extern __shared__ _Float16 dsm[];
    _Float16* recW   = dsm;           // 16384 f16
    _Float16* Wl     = dsm + 16384;   // 32768 f16: [64 gatecols][64 kchunks swz][8]
    _Float16* hstage = dsm + 49152;   // 1024 f16
    int tid = threadIdx.x;
    int wave = tid >> 6, lane = tid & 63, l15 = lane & 15, q = lane >> 4;
    int NI = 2 * S;
    int isl = blockIdx.x & (NI - 1);          // XCD-group: partners share bid%8
    int jblk = blockIdx.x >> (sbits + 1);
    int dir = isl >> sbits, strip = isl & (S - 1);

    const _Float16* Whh = dir ? WhhB : WhhF;
    const _Float16* W1  = dir ? W1B : W1F;
    const float* bias = dir ? bB : bF;

    #pragma unroll
    for (int it = 0; it < 8; ++it) {   // recW
        int idx = it * 256 + tid;
        int jj = idx >> 7, r = idx & 127;
        int g = r >> 5, c5 = r & 31;
        *(u32x4*)(recW + wseg(jj, g, c5) * 8) =
            *(const u32x4*)(Whh + (size_t)(g * 256 + jblk * 16 + jj) * 256 + c5 * 8);
    }
    #pragma unroll
    for (int it = 0; it < 16; ++it) {  // W1 slice: 64 gate-cols (4 gates x 16) of this jblk
        int idx = it * 256 + tid;
        int c = idx >> 6, cc = idx & 63;
        int grow = (c >> 4) * 256 + jblk * 16 + (c & 15);
        *(u32x4*)(Wl + ((size_t)c * 64 + (cc ^ (c & 7))) * 8) =
            *(const u32x4*)(W1 + (size_t)grow * 512 + cc * 8);
    }
    __syncthreads();

    float bs[4];
    #pragma unroll
    for (int g = 0; g < 4; ++g) bs[g] = bias[g * 256 + jblk * 16 + l15];

    f32x4 creg = { 0.f, 0.f, 0.f, 0.f };
    int arow = strip * 64 + wave * 16 + l15;

    // persistent prefetch registers; prologue fill for s=0 (waited by vmwait_pf at iter 0)
    f16x8 af[8]; u64 cb[8]; f16x8 ab[8];
    {
        int tp = dir ? 511 : 0;
        #pragma unroll
        for (int k0 = 0; k0 < 8; ++k0) {
            int jb = 2 * k0 + (q >> 1);
            size_t off = ((size_t)(tp * 16 + jb) * Bc + arow) * 16 + (q & 1) * 8;
            af[k0] = gload_c16(out0A + off);
            if (FP8) cb[k0] = gload_c8(out0B + off);
            else     ab[k0] = gload_c16((const _Float16*)out0B + off);
        }
    }

    #pragma unroll 1
    for (int s = 0; s < 512; ++s) {
        {   // wait partners' h[s] — one packed 64B flag line
            const int* sp = seq + ((s & 3) * NI + isl) * 16 + (lane & 15);
            for (;;) {
                int ok = 1;
                if (lane < 16) ok = (aload_i(sp) >= s);
                if (__all(ok)) break;
                __builtin_amdgcn_s_sleep(1);
            }
        }
        asm volatile("" ::: "memory");

        // prefetch regs valid beyond this point (register-tied fence; ~0 cost —
        // loads had the whole drain+barrier+prop window of step s-1 to land)
        if (FP8) vmwait_pf_fp8(af[0], af[1], af[2], af[3], af[4], af[5], af[6], af[7],
                               cb[0], cb[1], cb[2], cb[3], cb[4], cb[5], cb[6], cb[7]);
        else     vmwait_pf_f16(af[0], af[1], af[2], af[3], af[4], af[5], af[6], af[7],
                               ab[0], ab[1], ab[2], ab[3], ab[4], ab[5], ab[6], ab[7]);

        // issue 8 h-frag LLC loads first (their latency is hidden by G1 MFMAs below)
        const _Float16* hb = hring + (((size_t)((s & 3) * 2 + dir) * S + strip) * 16) * 1024;
        f16x8 ah[8];
        #pragma unroll
        for (int k0 = 0; k0 < 8; ++k0)
            ah[k0] = gload_h(hb + (size_t)(2 * k0 + (q >> 1)) * 1024 + (wave * 16 + l15) * 16 + (q & 1) * 8);

        // G1 slice from prefetched registers
        f32x4 acc[4];
        #pragma unroll
        for (int g = 0; g < 4; ++g) { f32x4 v = { bs[g], bs[g], bs[g], bs[g] }; acc[g] = v; }
        #pragma unroll
        for (int k0 = 0; k0 < 8; ++k0) {
            int c5 = k0 * 4 + q;
            #pragma unroll
            for (int g = 0; g < 4; ++g) {
                int col = g * 16 + l15;
                f16x8 bb = *(const f16x8*)(Wl + ((size_t)col * 64 + (c5 ^ (col & 7))) * 8);
                acc[g] = mfma16(af[k0], bb, acc[g]);
            }
        }
        #pragma unroll
        for (int k0 = 0; k0 < 8; ++k0) {
            f16x8 aa;
            if (FP8) aa = unpk_fp8x8(cb[k0]);
            else     aa = ab[k0];
            int c5 = (k0 + 8) * 4 + q;
            #pragma unroll
            for (int g = 0; g < 4; ++g) {
                int col = g * 16 + l15;
                f16x8 bb = *(const f16x8*)(Wl + ((size_t)col * 64 + (c5 ^ (col & 7))) * 8);
                acc[g] = mfma16(aa, bb, acc[g]);
            }
        }

        // exact drain: only the 8 h loads are outstanding here
        vmwait8(ah[0], ah[1], ah[2], ah[3], ah[4], ah[5], ah[6], ah[7]);

        #pragma unroll
        for (int k0 = 0; k0 < 8; ++k0) {
            int c5 = k0 * 4 + q;
            #pragma unroll
            for (int g = 0; g < 4; ++g)
                acc[g] = mfma16(ah[k0], *(const f16x8*)(recW + wseg(l15, g, c5) * 8), acc[g]);
        }
        // epilogue
        #pragma unroll
        for (int e = 0; e < 4; ++e) {
            int rl = wave * 16 + q * 4 + e;
            float cn = sigm(acc[1][e]) * creg[e] + sigm(acc[0][e]) * tanh_(acc[2][e]);
            creg[e] = cn;
            hstage[rl * 16 + l15] = (_Float16)(sigm(acc[3][e]) * tanh_(cn));
        }
        __syncthreads();
        {
            _Float16* wb = hring + ((((size_t)(((s + 1) & 3) * 2 + dir) * S + strip) * 16) + jblk) * 1024;
            gstore_u64((u64*)wb + tid, ((const u64*)hstage)[tid]);
        }
        // drains only the h-store (prefetch not yet issued) — fast flag post
        asm volatile("s_waitcnt vmcnt(0)" ::: "memory");
        __syncthreads();
        if (tid == 0)
            astore_i(seq + (((s + 1) & 3) * NI + isl) * 16 + jblk, s + 1);

        // NOW issue next step's out0 prefetch (16 loads) — flies during next poll
        {
            int tn = (dir ? (510 - s) : (s + 1)) & 511;   // clamped at s=511 (data unused)
            #pragma unroll
            for (int k0 = 0; k0 < 8; ++k0) {
                int jb = 2 * k0 + (q >> 1);
                size_t off = ((size_t)(tn * 16 + jb) * Bc + arow) * 16 + (q & 1) * 8;
                af[k0] = gload_c16(out0A + off);
                if (FP8) cb[k0] = gload_c8(out0B + off);
                else     ab[k0] = gload_c16((const _Float16*)out0B + off);
            }
        }
    }
}

// ---------------- final FC ----------------
__global__ __launch_bounds__(64) void fc_kernel(
    int S, const _Float16* __restrict__ hring,
    const float* __restrict__ fcwT, const float* __restrict__ fcb,
    float* __restrict__ out, int b0)
{
    __shared__ float hc[512];
    int b = blockIdx.x, l = threadIdx.x;
    int strip = b >> 6, row = b & 63;
    #pragma unroll
    for (int u = 0; u < 2; ++u) {
        int ui = l * 2 + u;
        int d = ui >> 6, rem = ui & 63;
        int jb = rem >> 2, part = rem & 3;
        const _Float16* hp = hring + (((size_t)d * S + strip) * 16 + jb) * 1024 + row * 16 + part * 4;
        union { u64 x; _Float16 h[4]; } c; c.x = aload_u64(hp);
        #pragma unroll
        for (int k = 0; k < 4; ++k)
            hc[d * 256 + jb * 16 + part * 4 + k] = (float)c.h[k];
    }
    __syncthreads();
    float acc = fcb[l];
    for (int j = 0; j < 512; ++j) acc += hc[j] * fcwT[j * 64 + l];
    out[(b0 + b) * 64 + l] = acc;
}

// ---------------- host ----------------
extern "C" void kernel_launch(void* const* d_in, const int* in_sizes, int n_in,
                              void* d_out, int out_size, void* d_ws, size_t ws_size,
                              hipStream_t stream)
{
    const float* x     = (const float*)d_in[0];
    const float* wih0f = (const float*)d_in[1];
    const float* whh0f = (const float*)d_in[2];
    const float* b0f   = (const float*)d_in[3];
    const float* wih0b = (const float*)d_in[4];
    const float* whh0b = (const float*)d_in[5];
    const float* b0b   = (const float*)d_in[6];
    const float* wih1f = (const float*)d_in[7];
    const float* whh1f = (const float*)d_in[8];
    const float* b1f   = (const float*)d_in[9];
    const float* wih1b = (const float*)d_in[10];
    const float* whh1b = (const float*)d_in[11];
    const float* b1b   = (const float*)d_in[12];
    const float* fcw   = (const float*)d_in[13];
    const float* fcb   = (const float*)d_in[14];
    float* out = (float*)d_out;
    (void)in_sizes; (void)n_in; (void)out_size;

    // workspace ladder: A = Bc512 all-f16 out0, B = Bc512 f16+fp8 split, D = Bc256 all-f16 (nb=2)
    auto totalFor = [](int bc, int f8) -> size_t {
        size_t s = (size_t)bc / 64;
        size_t fixed = 4 * 524288ull + 2 * 65536ull + 2 * 1048576ull
                     + 16777216ull + 131072ull + 4096ull + 65536ull; // + align slack
        return fixed + 262144ull * s
             + 262144ull * (size_t)bc                       // out0A f16
             + (f8 ? 131072ull : 262144ull) * (size_t)bc;   // out0B
    };
    int Bc = 512, useFp8 = 0;
    if (ws_size >= totalFor(512, 0))      { Bc = 512; useFp8 = 0; }
    else if (ws_size >= totalFor(512, 1)) { Bc = 512; useFp8 = 1; }
    else                                  { Bc = 256; useFp8 = 0; }
    while (Bc > 64 && ws_size < totalFor(Bc, useFp8)) Bc >>= 1;  // safety
    const int S = Bc / 64;
    const int nb = 512 / Bc;
    const int sbits = 31 - __builtin_clz((unsigned)S);

    char* pp = (char*)d_ws;
    auto alloc = [&](size_t bytes) -> void* {
        void* r = (void*)pp;
        pp += (bytes + 255) & ~(size_t)255;
        return r;
    };
    _Float16* Whh0f16 = (_Float16*)alloc(524288);
    _Float16* Whh0b16 = (_Float16*)alloc(524288);
    _Float16* Whh1f16 = (_Float16*)alloc(524288);
    _Float16* Whh1b16 = (_Float16*)alloc(524288);
    _Float16* Wih0pf  = (_Float16*)alloc(65536);
    _Float16* Wih0pb  = (_Float16*)alloc(65536);
    _Float16* Wih1f16 = (_Float16*)alloc(1048576);
    _Float16* Wih1b16 = (_Float16*)alloc(1048576);
    _Float16* xpad    = (_Float16*)alloc((size_t)16777216);
    float*    fcwT    = (float*)alloc(131072);
    int*      seqA    = (int*)alloc(4096);
    _Float16* hring   = (_Float16*)alloc((size_t)262144 * S);
    _Float16* out0A   = (_Float16*)alloc((size_t)262144 * Bc);
    unsigned char* out0B = (unsigned char*)alloc((useFp8 ? (size_t)131072 : (size_t)262144) * Bc);

    static int s_attr_done = 0;
    if (!s_attr_done) {
        (void)hipFuncSetAttribute(reinterpret_cast<const void*>(&l1_merged_t<0>),
                                  hipFuncAttributeMaxDynamicSharedMemorySize, 100352);
        (void)hipFuncSetAttribute(reinterpret_cast<const void*>(&l1_merged_t<1>),
                                  hipFuncAttributeMaxDynamicSharedMemorySize, 100352);
        s_attr_done = 1;
    }

    cvt_f16s<<<1024, 256, 0, stream>>>(whh0f, Whh0f16, 262144, 1.0f);
    cvt_f16s<<<1024, 256, 0, stream>>>(whh0b, Whh0b16, 262144, 1.0f);
    cvt_f16s<<<1024, 256, 0, stream>>>(whh1f, Whh1f16, 262144, 1.0f);
    cvt_f16s<<<1024, 256, 0, stream>>>(whh1b, Whh1b16, 262144, 1.0f);
    cvt_wih1<<<2048, 256, 0, stream>>>(wih1f, Wih1f16, 524288, useFp8);
    cvt_wih1<<<2048, 256, 0, stream>>>(wih1b, Wih1b16, 524288, useFp8);
    pad_wih0_f16<<<128, 256, 0, stream>>>(wih0f, Wih0pf);
    pad_wih0_f16<<<128, 256, 0, stream>>>(wih0b, Wih0pb);
    pad_x_f16<<<32768, 256, 0, stream>>>(x, xpad);
    transpose_fcw<<<128, 256, 0, stream>>>(fcw, fcwT);

    const size_t seqB   = 4096;
    const size_t hringB = (size_t)262144 * S;

    for (int bchunk = 0; bchunk < nb; ++bchunk) {
        int b0 = bchunk * Bc;

        (void)hipMemsetAsync(seqA, 0, seqB, stream);
        (void)hipMemsetAsync(hring, 0, hringB, stream);
        l0_persist<<<32 * S, 256, 0, stream>>>(S, sbits, Bc, b0, useFp8, xpad,
            Whh0f16, Whh0b16, Wih0pf, Wih0pb, b0f, b0b, hring, seqA, out0A, out0B);

        (void)hipMemsetAsync(seqA, 0, seqB, stream);
        (void)hipMemsetAsync(hring, 0, hringB, stream);
        if (useFp8)
            l1_merged_t<1><<<32 * S, 256, 100352, stream>>>(S, sbits, Bc, out0A, out0B,
                Whh1f16, Whh1b16, Wih1f16, Wih1b16, b1f, b1b, hring, seqA);
        else
            l1_merged_t<0><<<32 * S, 256, 100352, stream>>>(S, sbits, Bc, out0A, out0B,
                Whh1f16, Whh1b16, Wih1f16, Wih1b16, b1f, b1b, hring, seqA);

        fc_kernel<<<Bc, 64, 0, stream>>>(S, hring, fcwT, fcb, out, b0);
    }
}